// Round 10
// baseline (613.208 us; speedup 1.0000x reference)
//
#include <hip/hip_runtime.h>

#define NN 20000
#define EE 320000
#define KK 2000
#define KP 2048          // padded K-dim of E (zeros in 2000..2047)
#define SCALE 0.08838834764831845f
#define ZSPLIT 16        // attn_gemm partial slices
#define ACHUNKS 625      // 20000 / 32
#define ZCH 4            // s_gemm_exp k-chunks (4 * 512 = 2048)

typedef const float* cfp;
typedef __attribute__((ext_vector_type(8))) short sh8;
typedef __attribute__((ext_vector_type(4))) float f32x4;

static __device__ __forceinline__ float4 ld4(const float* p){ return *reinterpret_cast<const float4*>(p); }
static __device__ __forceinline__ void st4(float* p, float4 v){ *reinterpret_cast<float4*>(p) = v; }

static __device__ __forceinline__ unsigned short f2bf(float f){
    unsigned int u = __float_as_uint(f);
    u = (u + 0x7FFFu + ((u >> 16) & 1u)) >> 16;
    return (unsigned short)u;
}
static __device__ __forceinline__ float bf2f(unsigned short h){
    return __uint_as_float(((unsigned int)h) << 16);
}
static __device__ __forceinline__ sh8 lds8(const unsigned short* p){ return *reinterpret_cast<const sh8*>(p); }

// async global->LDS, 16B per lane; LDS dest is wave-uniform base + lane*16
static __device__ __forceinline__ void stage16(const unsigned short* g, unsigned short* l){
    __builtin_amdgcn_global_load_lds(
        (const __attribute__((address_space(1))) unsigned int*)g,
        (__attribute__((address_space(3))) unsigned int*)l, 16, 0, 0);
}

// ---------------- CSR build ----------------
__global__ __launch_bounds__(256) void k_count(const int* dst, int* deg){
    int i = blockIdx.x*256 + threadIdx.x;
    if (i < EE) atomicAdd(&deg[dst[i]], 1);
}

__global__ __launch_bounds__(256) void k_dinv(const int* deg, float* dinv){
    int n = blockIdx.x*256 + threadIdx.x;
    if (n < NN) dinv[n] = rsqrtf((float)deg[n] + 1.0f);
}

__global__ __launch_bounds__(1024) void k_scan(const int* cnt, int* rows){
    __shared__ int part[1024];
    int t = threadIdx.x;
    int base = t*20;
    int s = 0;
    for (int i = 0; i < 20; ++i){ int idx = base+i; if (idx < NN) s += cnt[idx]; }
    part[t] = s; __syncthreads();
    for (int off = 1; off < 1024; off <<= 1){
        int v = (t >= off) ? part[t-off] : 0;
        __syncthreads();
        part[t] += v;
        __syncthreads();
    }
    int run = part[t] - s;   // exclusive
    for (int i = 0; i < 20; ++i){
        int idx = base+i;
        if (idx < NN){ rows[idx] = run; run += cnt[idx]; }
    }
    if (t == 0) rows[NN] = EE;
}

__global__ __launch_bounds__(256) void k_fill(const int* src, const int* dst, const int* rows,
                                              int* cursor, int* col){
    int i = blockIdx.x*256 + threadIdx.x;
    if (i < EE){
        int d = dst[i];
        int pos = rows[d] + atomicAdd(&cursor[d], 1);
        col[pos] = src[i];
    }
}

// ---------------- weight transpose+convert ----------------
__global__ __launch_bounds__(256) void conv_wT(cfp w0, cfp w1, cfp w2, cfp w3, cfp w4, cfp w5, cfp w6,
                                               unsigned short* wts){
    const float* in;
    switch (blockIdx.z){
        case 0: in = w0; break; case 1: in = w1; break; case 2: in = w2; break;
        case 3: in = w3; break; case 4: in = w4; break; case 5: in = w5; break;
        default: in = w6; break;
    }
    unsigned short* out = wts + (size_t)blockIdx.z*16384;
    __shared__ float t[64][65];
    int r0 = blockIdx.x*64, c0 = blockIdx.y*64;
    int tid = threadIdx.x;
    for (int i = tid; i < 64*16; i += 256){
        int r = i >> 4, c4 = (i & 15) * 4;
        float4 v = ld4(in + (size_t)(r0+r)*128 + c0 + c4);
        t[r][c4+0]=v.x; t[r][c4+1]=v.y; t[r][c4+2]=v.z; t[r][c4+3]=v.w;
    }
    __syncthreads();
    for (int i = tid; i < 64*16; i += 256){
        int c = i >> 4, r4 = (i & 15) * 4;
        ushort4 o;
        o.x = f2bf(t[r4+0][c]); o.y = f2bf(t[r4+1][c]);
        o.z = f2bf(t[r4+2][c]); o.w = f2bf(t[r4+3][c]);
        *reinterpret_cast<ushort4*>(out + (size_t)(c0+c)*128 + r0 + r4) = o;
    }
}

// ---------------- fp32 GEMM (KK-sized only) ----------------
__global__ __launch_bounds__(512) void gemm128(const float* __restrict__ A, const float* __restrict__ Wm,
                                               float* __restrict__ C, int M,
                                               const float* bias, const float* resid, int relu){
    __shared__ __align__(16) float Ws[128*132];
    __shared__ float As[64*129];
    int tid = threadIdx.x;
    int r0 = blockIdx.x*64;
    for (int i = tid; i < 128*32; i += 512){
        int r = i >> 5, c4 = (i & 31) * 4;
        float4 v = ld4(Wm + r*128 + c4);
        st4(&Ws[r*132 + c4], v);
    }
    for (int i = tid; i < 64*32; i += 512){
        int r = i >> 5, c4 = (i & 31) * 4;
        float4 v = (r0 + r < M) ? ld4(A + (size_t)(r0+r)*128 + c4) : make_float4(0,0,0,0);
        As[r*129 + c4+0] = v.x; As[r*129 + c4+1] = v.y;
        As[r*129 + c4+2] = v.z; As[r*129 + c4+3] = v.w;
    }
    __syncthreads();
    int a = tid >> 5;
    int b = tid & 31;
    float acc[4][4] = {};
    #pragma unroll 4
    for (int d = 0; d < 128; ++d){
        float4 w = ld4(&Ws[d*132 + 4*b]);
        float wv[4] = {w.x, w.y, w.z, w.w};
        float av[4];
        #pragma unroll
        for (int i = 0; i < 4; ++i) av[i] = As[(4*a+i)*129 + d];
        #pragma unroll
        for (int i = 0; i < 4; ++i)
            #pragma unroll
            for (int j = 0; j < 4; ++j)
                acc[i][j] += av[i]*wv[j];
    }
    int cc = 4*b;
    #pragma unroll
    for (int i = 0; i < 4; ++i){
        int r = r0 + 4*a + i;
        if (r < M){
            float v[4];
            #pragma unroll
            for (int j = 0; j < 4; ++j) v[j] = acc[i][j];
            if (bias){
                #pragma unroll
                for (int j = 0; j < 4; ++j) v[j] += bias[cc+j];
            }
            if (relu){
                #pragma unroll
                for (int j = 0; j < 4; ++j) v[j] = fmaxf(v[j], 0.f);
            }
            if (resid){
                float4 rv = ld4(resid + (size_t)r*128 + cc);
                v[0]+=rv.x; v[1]+=rv.y; v[2]+=rv.z; v[3]+=rv.w;
            }
            st4(C + (size_t)r*128 + cc, make_float4(v[0],v[1],v[2],v[3]));
        }
    }
}

// ---------------- bf16 MFMA GEMM: C[M x 128] = (A@W)*rscale, bf16 out ----------------
__global__ __launch_bounds__(256) void tgemm(const unsigned short* __restrict__ A, int M,
                                             const unsigned short* __restrict__ Wt,
                                             const float* __restrict__ rscale,
                                             unsigned short* __restrict__ C){
    int tid = threadIdx.x;
    int wave = tid >> 6, lane = tid & 63;
    int wm = wave >> 1, wn = wave & 1;
    int m_base = blockIdx.x*64 + wm*32;
    int n_base = blockIdx.y*64 + wn*32;
    int l15 = lane & 15;
    int roff = (lane >> 4) * 8;
    const unsigned short* ap0 = A + (size_t)(m_base + l15)*128 + roff;
    const unsigned short* ap1 = ap0 + 16*128;
    const unsigned short* b0p = Wt + (size_t)(n_base + l15)*128 + roff;
    const unsigned short* b1p = b0p + 16*128;
    f32x4 acc00 = (f32x4)0.f, acc01 = (f32x4)0.f, acc10 = (f32x4)0.f, acc11 = (f32x4)0.f;
    #pragma unroll
    for (int r = 0; r < 128; r += 32){
        sh8 a0 = lds8(ap0 + r);
        sh8 a1 = lds8(ap1 + r);
        sh8 b0 = lds8(b0p + r);
        sh8 b1 = lds8(b1p + r);
        acc00 = __builtin_amdgcn_mfma_f32_16x16x32_bf16(a0, b0, acc00, 0, 0, 0);
        acc01 = __builtin_amdgcn_mfma_f32_16x16x32_bf16(a0, b1, acc01, 0, 0, 0);
        acc10 = __builtin_amdgcn_mfma_f32_16x16x32_bf16(a1, b0, acc10, 0, 0, 0);
        acc11 = __builtin_amdgcn_mfma_f32_16x16x32_bf16(a1, b1, acc11, 0, 0, 0);
    }
    int rq = (lane >> 4) * 4;
    f32x4 accs[2][2] = {{acc00, acc01},{acc10, acc11}};
    #pragma unroll
    for (int mi = 0; mi < 2; ++mi){
        #pragma unroll
        for (int ni = 0; ni < 2; ++ni){
            f32x4 a = accs[mi][ni];
            int gn = n_base + ni*16 + l15;
            #pragma unroll
            for (int reg = 0; reg < 4; ++reg){
                int gm = m_base + mi*16 + rq + reg;
                if (gm < M) C[(size_t)gm*128 + gn] = f2bf(a[reg] * (rscale ? rscale[gm] : 1.f));
            }
        }
    }
}

// ---------------- GCN aggregation (bf16 in, fp32 accumulate), neighbor unroll 8 ----------------
__global__ __launch_bounds__(256) void gcn_agg_bf(const unsigned short* __restrict__ y, const float* __restrict__ dinv,
                                                  const int* __restrict__ rows, const int* __restrict__ col,
                                                  const float* __restrict__ bias, void* __restrict__ outv,
                                                  int relu, int out_fp32){
    int wid = (int)((blockIdx.x*256 + threadIdx.x) >> 6);
    int lane = threadIdx.x & 63;
    if (wid >= NN) return;
    int f = lane*2;
    ushort2 u = *reinterpret_cast<const ushort2*>(y + (size_t)wid*128 + f);
    float ax = bf2f(u.x), ay = bf2f(u.y);
    int s = rows[wid], e = rows[wid+1];
    int j = s;
    int e8 = s + ((e - s) & ~7);
    for (; j < e8; j += 8){
        ushort2 v[8];
        #pragma unroll
        for (int q = 0; q < 8; ++q){
            int c = col[j+q];
            v[q] = *reinterpret_cast<const ushort2*>(y + (size_t)c*128 + f);
        }
        #pragma unroll
        for (int q = 0; q < 8; ++q){ ax += bf2f(v[q].x); ay += bf2f(v[q].y); }
    }
    for (; j < e; ++j){
        int c0 = col[j];
        ushort2 v0 = *reinterpret_cast<const ushort2*>(y + (size_t)c0*128 + f);
        ax += bf2f(v0.x); ay += bf2f(v0.y);
    }
    float dn = dinv[wid];
    float ox = ax*dn + bias[f];
    float oy = ay*dn + bias[f+1];
    if (relu){ ox = fmaxf(ox, 0.f); oy = fmaxf(oy, 0.f); }
    if (out_fp32){
        *reinterpret_cast<float2*>((float*)outv + (size_t)wid*128 + f) = make_float2(ox, oy);
    } else {
        ushort2 o; o.x = f2bf(ox); o.y = f2bf(oy);
        *reinterpret_cast<ushort2*>((unsigned short*)outv + (size_t)wid*128 + f) = o;
    }
}

// ---------------- convert fp32 -> bf16 ----------------
__global__ __launch_bounds__(256) void conv_bf16(const float* __restrict__ in, unsigned short* __restrict__ out, int n4){
    int i = blockIdx.x*256 + threadIdx.x;
    if (i < n4){
        float4 v = ld4(in + (size_t)i*4);
        ushort4 o;
        o.x = f2bf(v.x); o.y = f2bf(v.y); o.z = f2bf(v.z); o.w = f2bf(v.w);
        *reinterpret_cast<ushort4*>(out + (size_t)i*4) = o;
    }
}

// ---------------- convert + transpose (+ optional per-source-row scale) ----------------
__global__ __launch_bounds__(256) void conv_bf16_T(const float* __restrict__ in, unsigned short* __restrict__ out,
                                                   int M, int ldout, const float* __restrict__ rscale){
    __shared__ float t[64][65];
    int r0 = blockIdx.x*64, c0 = blockIdx.y*64;
    int tid = threadIdx.x;
    for (int i = tid; i < 64*16; i += 256){
        int r = i >> 4, c4 = (i & 15) * 4;
        float4 v = (r0 + r < M) ? ld4(in + (size_t)(r0+r)*128 + c0 + c4) : make_float4(0,0,0,0);
        if (rscale && r0 + r < M){
            float sc = rscale[r0 + r];
            v.x *= sc; v.y *= sc; v.z *= sc; v.w *= sc;
        }
        t[r][c4+0]=v.x; t[r][c4+1]=v.y; t[r][c4+2]=v.z; t[r][c4+3]=v.w;
    }
    __syncthreads();
    for (int i = tid; i < 64*16; i += 256){
        int c = i >> 4, r4 = (i & 15) * 4;
        if (r0 + r4 < M){
            ushort4 o;
            o.x = f2bf(t[r4+0][c]); o.y = f2bf(t[r4+1][c]);
            o.z = f2bf(t[r4+2][c]); o.w = f2bf(t[r4+3][c]);
            *reinterpret_cast<ushort4*>(out + (size_t)(c0+c)*ldout + r0 + r4) = o;
        }
    }
}

// ---------------- z reduction: zinv[n] = 1/sum, zdinv[n] = zinv[n]*dinv[n] ----------------
__global__ __launch_bounds__(256) void k_rcp32(const float* __restrict__ zp, const float* __restrict__ dinv,
                                               float* __restrict__ zinv, float* __restrict__ zdinv){
    int n = blockIdx.x*256 + threadIdx.x;
    if (n < NN){
        float s = 0.f;
        #pragma unroll
        for (int y = 0; y < ZCH; ++y) s += zp[(size_t)y*NN + n];
        float zi = 1.f / s;
        zinv[n] = zi;
        zdinv[n] = zi * dinv[n];
    }
}

// ---------------- S-GEMM + exp + z-partials ----------------
// grid (313 n-blocks, ZCH k-chunks of 512). ROW-PARTITIONED waves: each wave owns
// 16 rows x all 64 cols of the tile, end-to-end (MFMA -> exp -> private LDS ->
// 128B-contiguous global stores). No barriers in the k-loop; A-frags loaded once.
__global__ __launch_bounds__(256) void s_gemm_exp(const unsigned short* __restrict__ Kb,
                                                  const unsigned short* __restrict__ Qb2,
                                                  unsigned short* __restrict__ E, float* __restrict__ zpart){
    __shared__ unsigned short Es[4][16*68];   // per-wave 16 rows x 64 cols, pad 68 (2-mod-32 dword stride)
    __shared__ float zsh[64];
    int tid = threadIdx.x;
    int wave = tid >> 6, lane = tid & 63;
    int n_blk = blockIdx.x*64;
    int k_base = blockIdx.y*512;
    int l15 = lane & 15;
    int h = lane >> 4;
    int roff = h * 8;
    int rq = h * 4;
    unsigned short* myEs = Es[wave];
    // Kd fragments: wave's 16 rows, loaded ONCE for the whole block
    const unsigned short* ap = Kb + (size_t)(n_blk + wave*16 + l15)*128 + roff;
    sh8 a[4];
    #pragma unroll
    for (int r = 0; r < 4; ++r) a[r] = lds8(ap + r*32);
    float zacc[4] = {0.f, 0.f, 0.f, 0.f};
    for (int kb = 0; kb < 8; ++kb){
        int kcol = k_base + kb*64;
        f32x4 acc[4];
        #pragma unroll
        for (int ni = 0; ni < 4; ++ni) acc[ni] = (f32x4)0.f;
        const unsigned short* qb = Qb2 + (size_t)(kcol + l15)*128 + roff;
        #pragma unroll
        for (int r = 0; r < 4; ++r){
            #pragma unroll
            for (int ni = 0; ni < 4; ++ni){
                sh8 b = lds8(qb + (size_t)(ni*16)*128 + r*32);
                acc[ni] = __builtin_amdgcn_mfma_f32_16x16x32_bf16(a[r], b, acc[ni], 0, 0, 0);
            }
        }
        // exp + write own 16x64 quadrant to private LDS
        #pragma unroll
        for (int ni = 0; ni < 4; ++ni){
            f32x4 v = acc[ni];
            bool kv = (kcol + ni*16 + l15) < KK;
            #pragma unroll
            for (int reg = 0; reg < 4; ++reg){
                float e = kv ? __expf(v[reg]*SCALE) : 0.f;
                myEs[(rq + reg)*68 + ni*16 + l15] = f2bf(e);
                zacc[reg] += e;
            }
        }
        // read back (b128) and store to global in 128B-contiguous row segments
        #pragma unroll
        for (int it = 0; it < 2; ++it){
            int r = it*8 + (lane >> 3);          // 0..15
            int c8 = (lane & 7) * 8;             // 8 lanes x 8 ushorts = 128B per row
            sh8 v = lds8(myEs + r*68 + c8);
            int gr = n_blk + wave*16 + r;
            if (gr < NN)
                *reinterpret_cast<sh8*>(E + (size_t)gr*KP + kcol + c8) = v;
        }
    }
    // z: lane (h,l15) holds rows rq+reg over cols {ni*16+l15}; reduce across l15 group
    #pragma unroll
    for (int reg = 0; reg < 4; ++reg){
        float v = zacc[reg];
        v += __shfl_xor(v, 1);
        v += __shfl_xor(v, 2);
        v += __shfl_xor(v, 4);
        v += __shfl_xor(v, 8);
        zacc[reg] = v;
    }
    if (l15 == 0){
        #pragma unroll
        for (int reg = 0; reg < 4; ++reg)
            zsh[wave*16 + rq + reg] = zacc[reg];
    }
    __syncthreads();
    if (tid < 64){
        int n = n_blk + tid;
        if (n < NN) zpart[(size_t)blockIdx.y*NN + n] = zsh[tid];
    }
}

// ---------------- attn GEMM partials with depth-2 prefetch ----------------
__global__ __launch_bounds__(256) void attn_gemm(const unsigned short* __restrict__ E,
                                                 const unsigned short* __restrict__ Vt,
                                                 float* __restrict__ part){
    __shared__ unsigned short As[64*36];
    int tid = threadIdx.x;
    int wave = tid >> 6, lane = tid & 63;
    int kk0 = blockIdx.x*64;
    int per = (ACHUNKS + ZSPLIT - 1) / ZSPLIT;
    int c0 = blockIdx.y*per;
    int c1 = min(ACHUNKS, c0 + per);
    int l15 = lane & 15;
    int q8 = (lane >> 4) * 8;
    int d0 = wave*32;
    int n_l = tid & 31;
    int k8 = (tid >> 5) * 8;
    f32x4 acc[4][2];
    #pragma unroll
    for (int g = 0; g < 4; ++g){ acc[g][0] = (f32x4)0.f; acc[g][1] = (f32x4)0.f; }
    const unsigned short* ebase = E + (size_t)n_l*KP + kk0 + k8;
    const unsigned short* vb0p = Vt + (size_t)(d0 + l15)*NN + q8;
    const unsigned short* vb1p = vb0p + (size_t)16*NN;
    // depth-2 register pipeline: cur (used this iter), nxt (next iter)
    sh8 e_c = lds8(ebase + (size_t)c0*32*KP);
    sh8 v0_c = lds8(vb0p + c0*32);
    sh8 v1_c = lds8(vb1p + c0*32);
    sh8 e_n = (sh8)0, v0_n = (sh8)0, v1_n = (sh8)0;
    if (c0 + 1 < c1){
        e_n  = lds8(ebase + (size_t)(c0+1)*32*KP);
        v0_n = lds8(vb0p + (c0+1)*32);
        v1_n = lds8(vb1p + (c0+1)*32);
    }
    for (int ch = c0; ch < c1; ++ch){
        unsigned short tmp[8];
        *reinterpret_cast<sh8*>(tmp) = e_c;
        #pragma unroll
        for (int j = 0; j < 8; ++j) As[(k8 + j)*36 + n_l] = tmp[j];
        __syncthreads();
        // issue depth-2 load; latency spans two barrier periods
        sh8 e_f = (sh8)0, v0_f = (sh8)0, v1_f = (sh8)0;
        if (ch + 2 < c1){
            e_f  = lds8(ebase + (size_t)(ch+2)*32*KP);
            v0_f = lds8(vb0p + (ch+2)*32);
            v1_f = lds8(vb1p + (ch+2)*32);
        }
        #pragma unroll
        for (int g = 0; g < 4; ++g){
            const unsigned short* ap = &As[(g*16 + l15)*36 + q8];
            union { struct { ushort4 lo, hi; } u; sh8 v; } af;
            af.u.lo = *reinterpret_cast<const ushort4*>(ap);
            af.u.hi = *reinterpret_cast<const ushort4*>(ap + 4);
            acc[g][0] = __builtin_amdgcn_mfma_f32_16x16x32_bf16(af.v, v0_c, acc[g][0], 0, 0, 0);
            acc[g][1] = __builtin_amdgcn_mfma_f32_16x16x32_bf16(af.v, v1_c, acc[g][1], 0, 0, 0);
        }
        __syncthreads();
        e_c = e_n;  v0_c = v0_n;  v1_c = v1_n;
        e_n = e_f;  v0_n = v0_f;  v1_n = v1_f;
    }
    float* pbase = part + (size_t)blockIdx.y*KK*128;
    int rq = (lane >> 4) * 4;
    #pragma unroll
    for (int g = 0; g < 4; ++g){
        #pragma unroll
        for (int ni = 0; ni < 2; ++ni){
            int d = d0 + ni*16 + l15;
            #pragma unroll
            for (int reg = 0; reg < 4; ++reg){
                int kk = kk0 + g*16 + rq + reg;
                if (kk < KK) pbase[(size_t)kk*128 + d] = acc[g][ni][reg];
            }
        }
    }
}

// ---------------- xout GEMM: full K=2048 sweep, LDS-staged E (swizzled), bf16 out fused with zdinv ----------------
// grid 625 blocks x 256 threads. Block: E rows [m_base, m_base+32), all 128 d-cols.
// E tile (32 rows x 128 k = 8KB) staged via global_load_lds, double-buffered.
// LDS layout: linear [row][kb], swizzle: LDS[row][kb] = E[row][kb ^ ((row&15)<<4)]
// (swizzle pre-applied to the GLOBAL source addr; read applies same XOR to the FULL in-row byte offset).
__global__ __launch_bounds__(256) void xout_gemm(const unsigned short* __restrict__ E,
                                                 const unsigned short* __restrict__ B,
                                                 const float* __restrict__ zdinv,
                                                 unsigned short* __restrict__ out){
    __shared__ __align__(16) unsigned short ebuf[2][4096];   // 2 x 8 KB
    int tid = threadIdx.x;
    int wave = tid >> 6, lane = tid & 63;
    int l15 = lane & 15;
    int h = lane >> 4;
    int m_base = blockIdx.x*32;
    int srow0 = wave*4 + h;            // issue 0 row (0..15)
    int skb0  = (l15*16) ^ ((srow0 & 15) << 4);
    int srow1 = 16 + srow0;            // issue 1 row (16..31)
    int skb1  = (l15*16) ^ ((srow1 & 15) << 4);
    const unsigned short* g0 = E + (size_t)(m_base + srow0)*KP + (skb0 >> 1);
    const unsigned short* g1 = E + (size_t)(m_base + srow1)*KP + (skb1 >> 1);
    unsigned short* l0 = &ebuf[0][wave*512];          // + issue*2048 ushorts
    unsigned short* l1 = &ebuf[1][wave*512];
    const unsigned short* bp0 = B + (size_t)(wave*32 + l15)*KP + h*8;
    const unsigned short* bp1 = bp0 + (size_t)16*KP;
    int rswz = l15 << 4;

    f32x4 acc[2][2];
    #pragma unroll
    for (int mi = 0; mi < 2; ++mi)
        #pragma unroll
        for (int ni = 0; ni < 2; ++ni) acc[mi][ni] = (f32x4)0.f;

    // prologue: stage tile 0, load B tile 0
    stage16(g0, l0);
    stage16(g1, l0 + 2048);
    sh8 b0[4], b1[4];
    #pragma unroll
    for (int s = 0; s < 4; ++s){ b0[s] = lds8(bp0 + s*32); b1[s] = lds8(bp1 + s*32); }
    __syncthreads();

    for (int t = 0; t < 16; ++t){
        if (t < 15){
            const unsigned short* ng0 = g0 + (t+1)*128;
            const unsigned short* ng1 = g1 + (t+1)*128;
            unsigned short* nl = (t & 1) ? l0 : l1;
            stage16(ng0, nl);
            stage16(ng1, nl + 2048);
        }
        sh8 nb0[4], nb1[4];
        if (t < 15){
            #pragma unroll
            for (int s = 0; s < 4; ++s){
                nb0[s] = lds8(bp0 + (t+1)*128 + s*32);
                nb1[s] = lds8(bp1 + (t+1)*128 + s*32);
            }
        } else {
            #pragma unroll
            for (int s = 0; s < 4; ++s){ nb0[s] = (sh8)0; nb1[s] = (sh8)0; }
        }
        const unsigned short* eb = (t & 1) ? ebuf[1] : ebuf[0];
        #pragma unroll
        for (int s = 0; s < 4; ++s){
            int ko = ((h*16 + s*64) ^ rswz) >> 1;     // ushort offset within row, stays < 128
            sh8 a0 = lds8(eb + l15*128 + ko);
            sh8 a1 = lds8(eb + (16 + l15)*128 + ko);
            acc[0][0] = __builtin_amdgcn_mfma_f32_16x16x32_bf16(a0, b0[s], acc[0][0], 0, 0, 0);
            acc[0][1] = __builtin_amdgcn_mfma_f32_16x16x32_bf16(a0, b1[s], acc[0][1], 0, 0, 0);
            acc[1][0] = __builtin_amdgcn_mfma_f32_16x16x32_bf16(a1, b0[s], acc[1][0], 0, 0, 0);
            acc[1][1] = __builtin_amdgcn_mfma_f32_16x16x32_bf16(a1, b1[s], acc[1][1], 0, 0, 0);
        }
        __syncthreads();
        #pragma unroll
        for (int s = 0; s < 4; ++s){ b0[s] = nb0[s]; b1[s] = nb1[s]; }
    }

    int rq = h*4;
    #pragma unroll
    for (int mi = 0; mi < 2; ++mi){
        #pragma unroll
        for (int ni = 0; ni < 2; ++ni){
            f32x4 a = acc[mi][ni];
            int d = wave*32 + ni*16 + l15;
            #pragma unroll
            for (int reg = 0; reg < 4; ++reg){
                int gm = m_base + mi*16 + rq + reg;
                out[(size_t)gm*128 + d] = f2bf(a[reg] * zdinv[gm]);
            }
        }
    }
}

// ---------------- LayerNorm over D=128 (with partial-sum input) ----------------
__global__ __launch_bounds__(128) void ln_ker(const float* __restrict__ in, int nparts,
                                              const float* __restrict__ resid,
                                              const float* __restrict__ g, const float* __restrict__ be,
                                              float* __restrict__ out){
    __shared__ float rs[128], rq[128];
    int r = blockIdx.x, t = threadIdx.x;
    float v = 0.f;
    for (int p = 0; p < nparts; ++p) v += in[(size_t)p*KK*128 + r*128 + t];
    if (resid) v += resid[r*128 + t];
    rs[t] = v; rq[t] = v*v;
    __syncthreads();
    for (int off = 64; off > 0; off >>= 1){
        if (t < off){ rs[t] += rs[t+off]; rq[t] += rq[t+off]; }
        __syncthreads();
    }
    float mean = rs[0]*(1.f/128.f);
    float var = rq[0]*(1.f/128.f) - mean*mean;
    out[r*128 + t] = (v - mean)*rsqrtf(var + 1e-5f)*g[t] + be[t];
}

// ---------------- launcher ----------------
extern "C" void kernel_launch(void* const* d_in, const int* in_sizes, int n_in,
                              void* d_out, int out_size, void* d_ws, size_t ws_size,
                              hipStream_t stream){
    cfp x  = (cfp)d_in[0];
    const int* ei = (const int*)d_in[1];
    const int* esrc = ei;
    const int* edst = ei + EE;
    cfp W1=(cfp)d_in[3], b1=(cfp)d_in[4], W2=(cfp)d_in[5], b2=(cfp)d_in[6];
    cfp S =(cfp)d_in[7];
    cfp Wq=(cfp)d_in[8],  bq=(cfp)d_in[9],  Wk=(cfp)d_in[10], bk=(cfp)d_in[11];
    cfp Wv=(cfp)d_in[12], bv=(cfp)d_in[13], Wo=(cfp)d_in[14], bo=(cfp)d_in[15];
    cfp g0=(cfp)d_in[16], be0=(cfp)d_in[17], g1=(cfp)d_in[18], be1=(cfp)d_in[19];
    cfp Wl=(cfp)d_in[20], bl=(cfp)d_in[21], W3=(cfp)d_in[22], b3=(cfp)d_in[23];
    cfp W4=(cfp)d_in[24], b4=(cfp)d_in[25], W5=(cfp)d_in[26], b5=(cfp)d_in[27];

    char* wsb = (char*)d_ws;
    const size_t MB = 1048576;
    int*   deg    = (int*)  (wsb + 0);
    float* dinv   = (float*)(wsb + 81920);
    int*   rows   = (int*)  (wsb + 163840);
    int*   cursor = (int*)  (wsb + 245760);
    int*   col    = (int*)  (wsb + 327680);
    float* Qb     = (float*)(wsb + 2*MB);
    float* o1     = (float*)(wsb + 3*MB);    // also xl3 (fp32)
    float* o2     = (float*)(wsb + 4*MB);
    float* o3     = (float*)(wsb + 5*MB);
    float* xlb    = (float*)(wsb + 6*MB);
    float* zpart  = (float*)(wsb + 7*MB);                 // ZCH x NN fp32
    float* zinv   = (float*)(wsb + 10*MB);
    float* zdinv  = (float*)(wsb + 10*MB + 131072);
    unsigned short* Wts  = (unsigned short*)(wsb + 10*MB + 262144);
    unsigned short* Qbf  = (unsigned short*)(wsb + 11*MB);
    unsigned short* xlt3 = (unsigned short*)(wsb + 11*MB + 524288);  // [128 x KP] bf16
    unsigned short* xbf = (unsigned short*)(wsb + 12*MB); // also h3
    unsigned short* h1  = (unsigned short*)(wsb + 17*MB); // also h4
    unsigned short* h2  = (unsigned short*)(wsb + 22*MB);
    unsigned short* ybuf= (unsigned short*)(wsb + 27*MB);
    unsigned short* Kbf = (unsigned short*)(wsb + 32*MB);
    unsigned short* Vtz = (unsigned short*)(wsb + 37*MB);
    // time-aliased region 42..62 MiB: NB3 (Vd fp32, 9.8 MiB) -> part (16 MiB)
    float* NB3    = (float*)(wsb + 42*MB);
    float* part   = (float*)(wsb + 42*MB);
    unsigned short* E = (unsigned short*)(wsb + 62*MB);   // [NN x KP] bf16 = 78.1 MiB -> ends ~140.1 MiB
    float* outp   = (float*)d_out;
    unsigned short* h3 = xbf;
    unsigned short* h4 = h1;

    (void)hipMemsetAsync(deg, 0, NN*sizeof(int), stream);
    (void)hipMemsetAsync(cursor, 0, NN*sizeof(int), stream);
    (void)hipMemsetAsync(xlt3, 0, 128*KP*sizeof(unsigned short), stream);  // pad cols must be finite

    // CSR build
    k_count<<<1250, 256, 0, stream>>>(edst, deg);
    k_dinv<<<79, 256, 0, stream>>>(deg, dinv);
    k_scan<<<1, 1024, 0, stream>>>(deg, rows);
    k_fill<<<1250, 256, 0, stream>>>(esrc, edst, rows, cursor, col);

    // weights -> bf16 transposed; x -> bf16
    conv_wT<<<dim3(2,2,7), 256, 0, stream>>>(W1, W2, Wk, Wv, W3, W4, W5, Wts);
    conv_bf16<<<2500, 256, 0, stream>>>(x, xbf, NN*32);
    unsigned short* W1t = Wts;
    unsigned short* W2t = Wts + 16384;
    unsigned short* Wkt = Wts + 2*16384;
    unsigned short* Wvt = Wts + 3*16384;
    unsigned short* W4t = Wts + 5*16384;
    unsigned short* W5t = Wts + 6*16384;

    const int GN = 313;   // ceil(NN/64)
    const int GK = 32;    // ceil(KK/64) == KP/64

    // GCN1
    tgemm<<<dim3(GN,2), 256, 0, stream>>>(xbf, NN, W1t, dinv, ybuf);
    gcn_agg_bf<<<5000, 256, 0, stream>>>(ybuf, dinv, rows, col, b1, h1, 1, 0);
    // GCN2 -> h2
    tgemm<<<dim3(GN,2), 256, 0, stream>>>(h1, NN, W2t, dinv, ybuf);
    gcn_agg_bf<<<5000, 256, 0, stream>>>(ybuf, dinv, rows, col, b2, h2, 1, 0);
    // Kd -> Kbf (bf16)
    tgemm<<<dim3(GN,2), 256, 0, stream>>>(h2, NN, Wkt, dinv, ybuf);
    gcn_agg_bf<<<5000, 256, 0, stream>>>(ybuf, dinv, rows, col, bk, Kbf, 0, 0);
    // Q = S@Wq + bq (fp32) -> Qbf
    gemm128<<<GK, 512, 0, stream>>>(S, Wq, Qb, KK, bq, nullptr, 0);
    conv_bf16<<<250, 256, 0, stream>>>(Qb, Qbf, KK*32);
    // E = exp(SCALE * Kd Q^T), z partials (row-partitioned waves, 128B store segments)
    s_gemm_exp<<<dim3(GN, ZCH), 256, 0, stream>>>(Kbf, Qbf, E, zpart);
    k_rcp32<<<79, 256, 0, stream>>>(zpart, dinv, zinv, zdinv);
    // Vd -> NB3 (fp32) -> Vtz (transposed bf16, pre-scaled by zinv[n])
    tgemm<<<dim3(GN,2), 256, 0, stream>>>(h2, NN, Wvt, dinv, ybuf);
    gcn_agg_bf<<<5000, 256, 0, stream>>>(ybuf, dinv, rows, col, bv, NB3, 0, 1);
    conv_bf16_T<<<dim3(GN, 2), 256, 0, stream>>>(NB3, Vtz, NN, NN, zinv);
    // attn partials (NB3 dead now; part aliases it)
    attn_gemm<<<dim3(GK, ZSPLIT), 256, 0, stream>>>(E, Vtz, part);
    // out = LN(sum(part) + Q)
    ln_ker<<<KK, 128, 0, stream>>>(part, ZSPLIT, Qb, g0, be0, o1);
    // o2 = o1 + relu(o1@Wo + bo)
    gemm128<<<GK, 512, 0, stream>>>(o1, Wo, o2, KK, bo, o1, 1);
    ln_ker<<<KK, 128, 0, stream>>>(o2, 1, nullptr, g1, be1, o3);
    // xl = o3@Wl + bl ; xl3 = xl @ W3  (GCN3 weight folded into the seed side)
    gemm128<<<GK, 512, 0, stream>>>(o3, Wl, xlb, KK, bl, nullptr, 0);
    gemm128<<<GK, 512, 0, stream>>>(xlb, W3, o1, KK, nullptr, nullptr, 0);
    conv_bf16_T<<<dim3(GK, 2), 256, 0, stream>>>(o1, xlt3, KK, KP, nullptr);
    // ybuf[n] = bf16(zinv*dinv*(E[n] @ xl3)) == GCN3 pre-agg activations (fused, no partials)
    xout_gemm<<<625, 256, 0, stream>>>(E, xlt3, zdinv, ybuf);
    // GCN3 aggregation
    gcn_agg_bf<<<5000, 256, 0, stream>>>(ybuf, dinv, rows, col, b3, h3, 1, 0);
    // GCN4
    tgemm<<<dim3(GN,2), 256, 0, stream>>>(h3, NN, W4t, dinv, ybuf);
    gcn_agg_bf<<<5000, 256, 0, stream>>>(ybuf, dinv, rows, col, b4, h4, 1, 0);
    // GCN5 -> d_out (fp32)
    tgemm<<<dim3(GN,2), 256, 0, stream>>>(h4, NN, W5t, dinv, ybuf);
    gcn_agg_bf<<<5000, 256, 0, stream>>>(ybuf, dinv, rows, col, b5, outp, 0, 1);
}

// Round 11
// 586.420 us; speedup vs baseline: 1.0457x; 1.0457x over previous
//
#include <hip/hip_runtime.h>

#define NN 20000
#define EE 320000
#define KK 2000
#define KP 2048          // padded K-dim (zeros in 2000..2047); E stored chunk-major [ZCH][NN][512]
#define SCALE 0.08838834764831845f
#define ZSPLIT 16        // attn_gemm partial slices
#define ACHUNKS 625      // 20000 / 32
#define ZCH 4            // s_gemm_exp k-chunks (4 * 512 = 2048)

typedef const float* cfp;
typedef __attribute__((ext_vector_type(8))) short sh8;
typedef __attribute__((ext_vector_type(4))) float f32x4;

static __device__ __forceinline__ float4 ld4(const float* p){ return *reinterpret_cast<const float4*>(p); }
static __device__ __forceinline__ void st4(float* p, float4 v){ *reinterpret_cast<float4*>(p) = v; }

static __device__ __forceinline__ unsigned short f2bf(float f){
    unsigned int u = __float_as_uint(f);
    u = (u + 0x7FFFu + ((u >> 16) & 1u)) >> 16;
    return (unsigned short)u;
}
static __device__ __forceinline__ float bf2f(unsigned short h){
    return __uint_as_float(((unsigned int)h) << 16);
}
static __device__ __forceinline__ sh8 lds8(const unsigned short* p){ return *reinterpret_cast<const sh8*>(p); }

// async global->LDS, 16B per lane; LDS dest is wave-uniform base + lane*16
static __device__ __forceinline__ void stage16(const unsigned short* g, unsigned short* l){
    __builtin_amdgcn_global_load_lds(
        (const __attribute__((address_space(1))) unsigned int*)g,
        (__attribute__((address_space(3))) unsigned int*)l, 16, 0, 0);
}

// ---------------- CSR build ----------------
__global__ __launch_bounds__(256) void k_count(const int* dst, int* deg){
    int i = blockIdx.x*256 + threadIdx.x;
    if (i < EE) atomicAdd(&deg[dst[i]], 1);
}

__global__ __launch_bounds__(256) void k_dinv(const int* deg, float* dinv){
    int n = blockIdx.x*256 + threadIdx.x;
    if (n < NN) dinv[n] = rsqrtf((float)deg[n] + 1.0f);
}

__global__ __launch_bounds__(1024) void k_scan(const int* cnt, int* rows){
    __shared__ int part[1024];
    int t = threadIdx.x;
    int base = t*20;
    int s = 0;
    for (int i = 0; i < 20; ++i){ int idx = base+i; if (idx < NN) s += cnt[idx]; }
    part[t] = s; __syncthreads();
    for (int off = 1; off < 1024; off <<= 1){
        int v = (t >= off) ? part[t-off] : 0;
        __syncthreads();
        part[t] += v;
        __syncthreads();
    }
    int run = part[t] - s;   // exclusive
    for (int i = 0; i < 20; ++i){
        int idx = base+i;
        if (idx < NN){ rows[idx] = run; run += cnt[idx]; }
    }
    if (t == 0) rows[NN] = EE;
}

__global__ __launch_bounds__(256) void k_fill(const int* src, const int* dst, const int* rows,
                                              int* cursor, int* col){
    int i = blockIdx.x*256 + threadIdx.x;
    if (i < EE){
        int d = dst[i];
        int pos = rows[d] + atomicAdd(&cursor[d], 1);
        col[pos] = src[i];
    }
}

// ---------------- weight transpose+convert ----------------
__global__ __launch_bounds__(256) void conv_wT(cfp w0, cfp w1, cfp w2, cfp w3, cfp w4, cfp w5, cfp w6,
                                               unsigned short* wts){
    const float* in;
    switch (blockIdx.z){
        case 0: in = w0; break; case 1: in = w1; break; case 2: in = w2; break;
        case 3: in = w3; break; case 4: in = w4; break; case 5: in = w5; break;
        default: in = w6; break;
    }
    unsigned short* out = wts + (size_t)blockIdx.z*16384;
    __shared__ float t[64][65];
    int r0 = blockIdx.x*64, c0 = blockIdx.y*64;
    int tid = threadIdx.x;
    for (int i = tid; i < 64*16; i += 256){
        int r = i >> 4, c4 = (i & 15) * 4;
        float4 v = ld4(in + (size_t)(r0+r)*128 + c0 + c4);
        t[r][c4+0]=v.x; t[r][c4+1]=v.y; t[r][c4+2]=v.z; t[r][c4+3]=v.w;
    }
    __syncthreads();
    for (int i = tid; i < 64*16; i += 256){
        int c = i >> 4, r4 = (i & 15) * 4;
        ushort4 o;
        o.x = f2bf(t[r4+0][c]); o.y = f2bf(t[r4+1][c]);
        o.z = f2bf(t[r4+2][c]); o.w = f2bf(t[r4+3][c]);
        *reinterpret_cast<ushort4*>(out + (size_t)(c0+c)*128 + r0 + r4) = o;
    }
}

// ---------------- fp32 GEMM (KK-sized only) ----------------
__global__ __launch_bounds__(512) void gemm128(const float* __restrict__ A, const float* __restrict__ Wm,
                                               float* __restrict__ C, int M,
                                               const float* bias, const float* resid, int relu){
    __shared__ __align__(16) float Ws[128*132];
    __shared__ float As[64*129];
    int tid = threadIdx.x;
    int r0 = blockIdx.x*64;
    for (int i = tid; i < 128*32; i += 512){
        int r = i >> 5, c4 = (i & 31) * 4;
        float4 v = ld4(Wm + r*128 + c4);
        st4(&Ws[r*132 + c4], v);
    }
    for (int i = tid; i < 64*32; i += 512){
        int r = i >> 5, c4 = (i & 31) * 4;
        float4 v = (r0 + r < M) ? ld4(A + (size_t)(r0+r)*128 + c4) : make_float4(0,0,0,0);
        As[r*129 + c4+0] = v.x; As[r*129 + c4+1] = v.y;
        As[r*129 + c4+2] = v.z; As[r*129 + c4+3] = v.w;
    }
    __syncthreads();
    int a = tid >> 5;
    int b = tid & 31;
    float acc[4][4] = {};
    #pragma unroll 4
    for (int d = 0; d < 128; ++d){
        float4 w = ld4(&Ws[d*132 + 4*b]);
        float wv[4] = {w.x, w.y, w.z, w.w};
        float av[4];
        #pragma unroll
        for (int i = 0; i < 4; ++i) av[i] = As[(4*a+i)*129 + d];
        #pragma unroll
        for (int i = 0; i < 4; ++i)
            #pragma unroll
            for (int j = 0; j < 4; ++j)
                acc[i][j] += av[i]*wv[j];
    }
    int cc = 4*b;
    #pragma unroll
    for (int i = 0; i < 4; ++i){
        int r = r0 + 4*a + i;
        if (r < M){
            float v[4];
            #pragma unroll
            for (int j = 0; j < 4; ++j) v[j] = acc[i][j];
            if (bias){
                #pragma unroll
                for (int j = 0; j < 4; ++j) v[j] += bias[cc+j];
            }
            if (relu){
                #pragma unroll
                for (int j = 0; j < 4; ++j) v[j] = fmaxf(v[j], 0.f);
            }
            if (resid){
                float4 rv = ld4(resid + (size_t)r*128 + cc);
                v[0]+=rv.x; v[1]+=rv.y; v[2]+=rv.z; v[3]+=rv.w;
            }
            st4(C + (size_t)r*128 + cc, make_float4(v[0],v[1],v[2],v[3]));
        }
    }
}

// ---------------- bf16 MFMA GEMM: C[M x 128] = (A@W)*rscale, bf16 out ----------------
__global__ __launch_bounds__(256) void tgemm(const unsigned short* __restrict__ A, int M,
                                             const unsigned short* __restrict__ Wt,
                                             const float* __restrict__ rscale,
                                             unsigned short* __restrict__ C){
    int tid = threadIdx.x;
    int wave = tid >> 6, lane = tid & 63;
    int wm = wave >> 1, wn = wave & 1;
    int m_base = blockIdx.x*64 + wm*32;
    int n_base = blockIdx.y*64 + wn*32;
    int l15 = lane & 15;
    int roff = (lane >> 4) * 8;
    const unsigned short* ap0 = A + (size_t)(m_base + l15)*128 + roff;
    const unsigned short* ap1 = ap0 + 16*128;
    const unsigned short* b0p = Wt + (size_t)(n_base + l15)*128 + roff;
    const unsigned short* b1p = b0p + 16*128;
    f32x4 acc00 = (f32x4)0.f, acc01 = (f32x4)0.f, acc10 = (f32x4)0.f, acc11 = (f32x4)0.f;
    #pragma unroll
    for (int r = 0; r < 128; r += 32){
        sh8 a0 = lds8(ap0 + r);
        sh8 a1 = lds8(ap1 + r);
        sh8 b0 = lds8(b0p + r);
        sh8 b1 = lds8(b1p + r);
        acc00 = __builtin_amdgcn_mfma_f32_16x16x32_bf16(a0, b0, acc00, 0, 0, 0);
        acc01 = __builtin_amdgcn_mfma_f32_16x16x32_bf16(a0, b1, acc01, 0, 0, 0);
        acc10 = __builtin_amdgcn_mfma_f32_16x16x32_bf16(a1, b0, acc10, 0, 0, 0);
        acc11 = __builtin_amdgcn_mfma_f32_16x16x32_bf16(a1, b1, acc11, 0, 0, 0);
    }
    int rq = (lane >> 4) * 4;
    f32x4 accs[2][2] = {{acc00, acc01},{acc10, acc11}};
    #pragma unroll
    for (int mi = 0; mi < 2; ++mi){
        #pragma unroll
        for (int ni = 0; ni < 2; ++ni){
            f32x4 a = accs[mi][ni];
            int gn = n_base + ni*16 + l15;
            #pragma unroll
            for (int reg = 0; reg < 4; ++reg){
                int gm = m_base + mi*16 + rq + reg;
                if (gm < M) C[(size_t)gm*128 + gn] = f2bf(a[reg] * (rscale ? rscale[gm] : 1.f));
            }
        }
    }
}

// ---------------- GCN aggregation (bf16 in, fp32 accumulate), neighbor unroll 8 ----------------
__global__ __launch_bounds__(256) void gcn_agg_bf(const unsigned short* __restrict__ y, const float* __restrict__ dinv,
                                                  const int* __restrict__ rows, const int* __restrict__ col,
                                                  const float* __restrict__ bias, void* __restrict__ outv,
                                                  int relu, int out_fp32){
    int wid = (int)((blockIdx.x*256 + threadIdx.x) >> 6);
    int lane = threadIdx.x & 63;
    if (wid >= NN) return;
    int f = lane*2;
    ushort2 u = *reinterpret_cast<const ushort2*>(y + (size_t)wid*128 + f);
    float ax = bf2f(u.x), ay = bf2f(u.y);
    int s = rows[wid], e = rows[wid+1];
    int j = s;
    int e8 = s + ((e - s) & ~7);
    for (; j < e8; j += 8){
        ushort2 v[8];
        #pragma unroll
        for (int q = 0; q < 8; ++q){
            int c = col[j+q];
            v[q] = *reinterpret_cast<const ushort2*>(y + (size_t)c*128 + f);
        }
        #pragma unroll
        for (int q = 0; q < 8; ++q){ ax += bf2f(v[q].x); ay += bf2f(v[q].y); }
    }
    for (; j < e; ++j){
        int c0 = col[j];
        ushort2 v0 = *reinterpret_cast<const ushort2*>(y + (size_t)c0*128 + f);
        ax += bf2f(v0.x); ay += bf2f(v0.y);
    }
    float dn = dinv[wid];
    float ox = ax*dn + bias[f];
    float oy = ay*dn + bias[f+1];
    if (relu){ ox = fmaxf(ox, 0.f); oy = fmaxf(oy, 0.f); }
    if (out_fp32){
        *reinterpret_cast<float2*>((float*)outv + (size_t)wid*128 + f) = make_float2(ox, oy);
    } else {
        ushort2 o; o.x = f2bf(ox); o.y = f2bf(oy);
        *reinterpret_cast<ushort2*>((unsigned short*)outv + (size_t)wid*128 + f) = o;
    }
}

// ---------------- convert fp32 -> bf16 ----------------
__global__ __launch_bounds__(256) void conv_bf16(const float* __restrict__ in, unsigned short* __restrict__ out, int n4){
    int i = blockIdx.x*256 + threadIdx.x;
    if (i < n4){
        float4 v = ld4(in + (size_t)i*4);
        ushort4 o;
        o.x = f2bf(v.x); o.y = f2bf(v.y); o.z = f2bf(v.z); o.w = f2bf(v.w);
        *reinterpret_cast<ushort4*>(out + (size_t)i*4) = o;
    }
}

// ---------------- convert + transpose (+ optional per-source-row scale) ----------------
__global__ __launch_bounds__(256) void conv_bf16_T(const float* __restrict__ in, unsigned short* __restrict__ out,
                                                   int M, int ldout, const float* __restrict__ rscale){
    __shared__ float t[64][65];
    int r0 = blockIdx.x*64, c0 = blockIdx.y*64;
    int tid = threadIdx.x;
    for (int i = tid; i < 64*16; i += 256){
        int r = i >> 4, c4 = (i & 15) * 4;
        float4 v = (r0 + r < M) ? ld4(in + (size_t)(r0+r)*128 + c0 + c4) : make_float4(0,0,0,0);
        if (rscale && r0 + r < M){
            float sc = rscale[r0 + r];
            v.x *= sc; v.y *= sc; v.z *= sc; v.w *= sc;
        }
        t[r][c4+0]=v.x; t[r][c4+1]=v.y; t[r][c4+2]=v.z; t[r][c4+3]=v.w;
    }
    __syncthreads();
    for (int i = tid; i < 64*16; i += 256){
        int c = i >> 4, r4 = (i & 15) * 4;
        if (r0 + r4 < M){
            ushort4 o;
            o.x = f2bf(t[r4+0][c]); o.y = f2bf(t[r4+1][c]);
            o.z = f2bf(t[r4+2][c]); o.w = f2bf(t[r4+3][c]);
            *reinterpret_cast<ushort4*>(out + (size_t)(c0+c)*ldout + r0 + r4) = o;
        }
    }
}

// ---------------- z reduction: zinv[n] = 1/sum, zdinv[n] = zinv[n]*dinv[n] ----------------
__global__ __launch_bounds__(256) void k_rcp32(const float* __restrict__ zp, const float* __restrict__ dinv,
                                               float* __restrict__ zinv, float* __restrict__ zdinv){
    int n = blockIdx.x*256 + threadIdx.x;
    if (n < NN){
        float s = 0.f;
        #pragma unroll
        for (int y = 0; y < ZCH; ++y) s += zp[(size_t)y*NN + n];
        float zi = 1.f / s;
        zinv[n] = zi;
        zdinv[n] = zi * dinv[n];
    }
}

// ---------------- S-GEMM + exp + z-partials ----------------
// grid (313 n-blocks, ZCH k-chunks of 512). r5's compute pipeline (reg-cached Kd,
// Q double-buffered, wave-private quadrants, no k-loop barriers) writing into a
// block-wide 64x512 LDS tile; ONE store phase at block end emits fully-contiguous
// 1KB-per-instruction rows into chunk-major E [ZCH][NN][512].
__global__ __launch_bounds__(256) void s_gemm_exp(const unsigned short* __restrict__ Kb,
                                                  const unsigned short* __restrict__ Qb2,
                                                  unsigned short* __restrict__ E, float* __restrict__ zpart){
    __shared__ __align__(16) unsigned short Eb[64*520];   // 64 rows x 512 cols, pad 520
    __shared__ float zsh[2][64];
    int tid = threadIdx.x;
    int wave = tid >> 6, lane = tid & 63;
    int wm = wave >> 1, wn = wave & 1;
    int n_blk = blockIdx.x*64;
    int k_base = blockIdx.y*512;
    int l15 = lane & 15;
    int h = lane >> 4;
    int roff = h * 8;
    int rq = h * 4;
    // Kd fragments (reused across all 8 k-blocks)
    const unsigned short* ap0 = Kb + (size_t)(n_blk + wm*32 + l15)*128 + roff;
    const unsigned short* ap1 = ap0 + 16*128;
    sh8 a0[4], a1[4];
    #pragma unroll
    for (int r = 0; r < 4; ++r){ a0[r] = lds8(ap0 + r*32); a1[r] = lds8(ap1 + r*32); }
    // Q fragments, double buffered
    const unsigned short* qbase = Qb2 + (size_t)(k_base + wn*32 + l15)*128 + roff;
    sh8 q0[4], q1[4];
    #pragma unroll
    for (int r = 0; r < 4; ++r){ q0[r] = lds8(qbase + r*32); q1[r] = lds8(qbase + 16*128 + r*32); }
    float zacc[2][4] = {{0.f,0.f,0.f,0.f},{0.f,0.f,0.f,0.f}};
    for (int kb = 0; kb < 8; ++kb){
        sh8 n0[4], n1[4];
        if (kb < 7){
            const unsigned short* qn = qbase + (size_t)(kb+1)*64*128;
            #pragma unroll
            for (int r = 0; r < 4; ++r){ n0[r] = lds8(qn + r*32); n1[r] = lds8(qn + 16*128 + r*32); }
        } else {
            #pragma unroll
            for (int r = 0; r < 4; ++r){ n0[r] = (sh8)0; n1[r] = (sh8)0; }
        }
        f32x4 acc00 = (f32x4)0.f, acc01 = (f32x4)0.f, acc10 = (f32x4)0.f, acc11 = (f32x4)0.f;
        #pragma unroll
        for (int r = 0; r < 4; ++r){
            acc00 = __builtin_amdgcn_mfma_f32_16x16x32_bf16(a0[r], q0[r], acc00, 0, 0, 0);
            acc01 = __builtin_amdgcn_mfma_f32_16x16x32_bf16(a0[r], q1[r], acc01, 0, 0, 0);
            acc10 = __builtin_amdgcn_mfma_f32_16x16x32_bf16(a1[r], q0[r], acc10, 0, 0, 0);
            acc11 = __builtin_amdgcn_mfma_f32_16x16x32_bf16(a1[r], q1[r], acc11, 0, 0, 0);
        }
        int kcol = kb*64;   // within-chunk column base
        f32x4 accs[2][2] = {{acc00, acc01},{acc10, acc11}};
        // exp + write own quadrant into the block-wide tile (rows wm*32.., cols kcol+wn*32..)
        #pragma unroll
        for (int mi = 0; mi < 2; ++mi){
            #pragma unroll
            for (int ni = 0; ni < 2; ++ni){
                f32x4 a = accs[mi][ni];
                bool kv = (k_base + kcol + wn*32 + ni*16 + l15) < KK;
                #pragma unroll
                for (int reg = 0; reg < 4; ++reg){
                    float e = kv ? __expf(a[reg]*SCALE) : 0.f;
                    Eb[(wm*32 + mi*16 + rq + reg)*520 + kcol + wn*32 + ni*16 + l15] = f2bf(e);
                    zacc[mi][reg] += e;
                }
            }
        }
        #pragma unroll
        for (int r = 0; r < 4; ++r){ q0[r] = n0[r]; q1[r] = n1[r]; }
    }
    // z reduction (r5 scheme)
    #pragma unroll
    for (int mi = 0; mi < 2; ++mi){
        #pragma unroll
        for (int reg = 0; reg < 4; ++reg){
            float v = zacc[mi][reg];
            v += __shfl_xor(v, 1);
            v += __shfl_xor(v, 2);
            v += __shfl_xor(v, 4);
            v += __shfl_xor(v, 8);
            zacc[mi][reg] = v;
        }
    }
    if (l15 == 0){
        #pragma unroll
        for (int mi = 0; mi < 2; ++mi)
            #pragma unroll
            for (int reg = 0; reg < 4; ++reg)
                zsh[wn][wm*32 + mi*16 + h*4 + reg] = zacc[mi][reg];
    }
    __syncthreads();   // all quadrants in Eb + zsh complete
    if (tid < 64){
        int n = n_blk + tid;
        if (n < NN) zpart[(size_t)blockIdx.y*NN + n] = zsh[0][tid] + zsh[1][tid];
    }
    // store phase: wave stores whole rows, 64 lanes x 16B = 1KB contiguous per instruction
    unsigned short* ebase = E + ((size_t)blockIdx.y*NN + n_blk)*512;
    #pragma unroll
    for (int it = 0; it < 16; ++it){
        int row = it*4 + wave;
        sh8 v = lds8(Eb + row*520 + lane*8);
        if (n_blk + row < NN)
            *reinterpret_cast<sh8*>(ebase + (size_t)row*512 + lane*8) = v;
    }
}

// ---------------- attn GEMM partials (depth-1 prefetch, r5 schedule; chunk-major E) ----------------
__global__ __launch_bounds__(256) void attn_gemm(const unsigned short* __restrict__ E,
                                                 const unsigned short* __restrict__ Vt,
                                                 float* __restrict__ part){
    __shared__ unsigned short As[64*36];
    int tid = threadIdx.x;
    int wave = tid >> 6, lane = tid & 63;
    int kk0 = blockIdx.x*64;
    int kch = kk0 >> 9;            // E chunk index
    int ko  = kk0 & 511;           // offset within chunk
    int per = (ACHUNKS + ZSPLIT - 1) / ZSPLIT;
    int c0 = blockIdx.y*per;
    int c1 = min(ACHUNKS, c0 + per);
    int l15 = lane & 15;
    int q8 = (lane >> 4) * 8;
    int d0 = wave*32;
    int n_l = tid & 31;
    int k8 = (tid >> 5) * 8;
    f32x4 acc[4][2];
    #pragma unroll
    for (int g = 0; g < 4; ++g){ acc[g][0] = (f32x4)0.f; acc[g][1] = (f32x4)0.f; }
    const unsigned short* ebase = E + ((size_t)kch*NN + n_l)*512 + ko + k8;
    const unsigned short* vb0p = Vt + (size_t)(d0 + l15)*NN + q8;
    const unsigned short* vb1p = vb0p + (size_t)16*NN;
    sh8 etmp = lds8(ebase + (size_t)c0*32*512);
    sh8 vb0 = lds8(vb0p + c0*32);
    sh8 vb1 = lds8(vb1p + c0*32);
    for (int ch = c0; ch < c1; ++ch){
        unsigned short tmp[8];
        *reinterpret_cast<sh8*>(tmp) = etmp;
        #pragma unroll
        for (int j = 0; j < 8; ++j) As[(k8 + j)*36 + n_l] = tmp[j];
        __syncthreads();
        sh8 etn = (sh8)0, vbn0 = (sh8)0, vbn1 = (sh8)0;
        if (ch + 1 < c1){
            etn  = lds8(ebase + (size_t)(ch+1)*32*512);
            vbn0 = lds8(vb0p + (ch+1)*32);
            vbn1 = lds8(vb1p + (ch+1)*32);
        }
        #pragma unroll
        for (int g = 0; g < 4; ++g){
            const unsigned short* ap = &As[(g*16 + l15)*36 + q8];
            union { struct { ushort4 lo, hi; } u; sh8 v; } af;
            af.u.lo = *reinterpret_cast<const ushort4*>(ap);
            af.u.hi = *reinterpret_cast<const ushort4*>(ap + 4);
            acc[g][0] = __builtin_amdgcn_mfma_f32_16x16x32_bf16(af.v, vb0, acc[g][0], 0, 0, 0);
            acc[g][1] = __builtin_amdgcn_mfma_f32_16x16x32_bf16(af.v, vb1, acc[g][1], 0, 0, 0);
        }
        __syncthreads();
        etmp = etn; vb0 = vbn0; vb1 = vbn1;
    }
    float* pbase = part + (size_t)blockIdx.y*KK*128;
    int rq = (lane >> 4) * 4;
    #pragma unroll
    for (int g = 0; g < 4; ++g){
        #pragma unroll
        for (int ni = 0; ni < 2; ++ni){
            int d = d0 + ni*16 + l15;
            #pragma unroll
            for (int reg = 0; reg < 4; ++reg){
                int kk = kk0 + g*16 + rq + reg;
                if (kk < KK) pbase[(size_t)kk*128 + d] = acc[g][ni][reg];
            }
        }
    }
}

// ---------------- xout GEMM: full K=2048 sweep, LDS-staged chunk-major E (swizzled), bf16 out fused ----------------
// grid 625 blocks x 256 threads. Block: E rows [m_base, m_base+32), all 128 d-cols.
// Per tile t (128 k): chunk = t>>2, within-chunk offset = (t&3)*128.
__global__ __launch_bounds__(256) void xout_gemm(const unsigned short* __restrict__ E,
                                                 const unsigned short* __restrict__ B,
                                                 const float* __restrict__ zdinv,
                                                 unsigned short* __restrict__ out){
    __shared__ __align__(16) unsigned short ebuf[2][4096];   // 2 x 8 KB
    int tid = threadIdx.x;
    int wave = tid >> 6, lane = tid & 63;
    int l15 = lane & 15;
    int h = lane >> 4;
    int m_base = blockIdx.x*32;
    int srow0 = wave*4 + h;            // issue 0 row (0..15)
    int skb0  = (l15*16) ^ ((srow0 & 15) << 4);
    int srow1 = 16 + srow0;            // issue 1 row (16..31)
    int skb1  = (l15*16) ^ ((srow1 & 15) << 4);
    unsigned short* l0 = &ebuf[0][wave*512];          // + issue*2048 ushorts
    unsigned short* l1 = &ebuf[1][wave*512];
    const unsigned short* bp0 = B + (size_t)(wave*32 + l15)*KP + h*8;
    const unsigned short* bp1 = bp0 + (size_t)16*KP;
    int rswz = l15 << 4;
    // per-tile global source addresses (chunk-major E)
    #define EADDR(t, srow, skb) (E + (((size_t)((t) >> 2))*NN + m_base + (srow))*512 + ((t) & 3)*128 + ((skb) >> 1))

    f32x4 acc[2][2];
    #pragma unroll
    for (int mi = 0; mi < 2; ++mi)
        #pragma unroll
        for (int ni = 0; ni < 2; ++ni) acc[mi][ni] = (f32x4)0.f;

    // prologue: stage tile 0, load B tile 0
    stage16(EADDR(0, srow0, skb0), l0);
    stage16(EADDR(0, srow1, skb1), l0 + 2048);
    sh8 b0[4], b1[4];
    #pragma unroll
    for (int s = 0; s < 4; ++s){ b0[s] = lds8(bp0 + s*32); b1[s] = lds8(bp1 + s*32); }
    __syncthreads();

    for (int t = 0; t < 16; ++t){
        if (t < 15){
            unsigned short* nl = (t & 1) ? l0 : l1;
            stage16(EADDR(t+1, srow0, skb0), nl);
            stage16(EADDR(t+1, srow1, skb1), nl + 2048);
        }
        sh8 nb0[4], nb1[4];
        if (t < 15){
            #pragma unroll
            for (int s = 0; s < 4; ++s){
                nb0[s] = lds8(bp0 + (t+1)*128 + s*32);
                nb1[s] = lds8(bp1 + (t+1)*128 + s*32);
            }
        } else {
            #pragma unroll
            for (int s = 0; s < 4; ++s){ nb0[s] = (sh8)0; nb1[s] = (sh8)0; }
        }
        const unsigned short* eb = (t & 1) ? ebuf[1] : ebuf[0];
        #pragma unroll
        for (int s = 0; s < 4; ++s){
            int ko = ((h*16 + s*64) ^ rswz) >> 1;     // ushort offset within row, stays < 128
            sh8 a0 = lds8(eb + l15*128 + ko);
            sh8 a1 = lds8(eb + (16 + l15)*128 + ko);
            acc[0][0] = __builtin_amdgcn_mfma_f32_16x16x32_bf16(a0, b0[s], acc[0][0], 0, 0, 0);
            acc[0][1] = __builtin_amdgcn_mfma_f32_16x16x32_bf16(a0, b1[s], acc[0][1], 0, 0, 0);
            acc[1][0] = __builtin_amdgcn_mfma_f32_16x16x32_bf16(a1, b0[s], acc[1][0], 0, 0, 0);
            acc[1][1] = __builtin_amdgcn_mfma_f32_16x16x32_bf16(a1, b1[s], acc[1][1], 0, 0, 0);
        }
        __syncthreads();
        #pragma unroll
        for (int s = 0; s < 4; ++s){ b0[s] = nb0[s]; b1[s] = nb1[s]; }
    }
    #undef EADDR

    int rq = h*4;
    #pragma unroll
    for (int mi = 0; mi < 2; ++mi){
        #pragma unroll
        for (int ni = 0; ni < 2; ++ni){
            f32x4 a = acc[mi][ni];
            int d = wave*32 + ni*16 + l15;
            #pragma unroll
            for (int reg = 0; reg < 4; ++reg){
                int gm = m_base + mi*16 + rq + reg;
                out[(size_t)gm*128 + d] = f2bf(a[reg] * zdinv[gm]);
            }
        }
    }
}

// ---------------- LayerNorm over D=128 (with partial-sum input) ----------------
__global__ __launch_bounds__(128) void ln_ker(const float* __restrict__ in, int nparts,
                                              const float* __restrict__ resid,
                                              const float* __restrict__ g, const float* __restrict__ be,
                                              float* __restrict__ out){
    __shared__ float rs[128], rq[128];
    int r = blockIdx.x, t = threadIdx.x;
    float v = 0.f;
    for (int p = 0; p < nparts; ++p) v += in[(size_t)p*KK*128 + r*128 + t];
    if (resid) v += resid[r*128 + t];
    rs[t] = v; rq[t] = v*v;
    __syncthreads();
    for (int off = 64; off > 0; off >>= 1){
        if (t < off){ rs[t] += rs[t+off]; rq[t] += rq[t+off]; }
        __syncthreads();
    }
    float mean = rs[0]*(1.f/128.f);
    float var = rq[0]*(1.f/128.f) - mean*mean;
    out[r*128 + t] = (v - mean)*rsqrtf(var + 1e-5f)*g[t] + be[t];
}

// ---------------- launcher ----------------
extern "C" void kernel_launch(void* const* d_in, const int* in_sizes, int n_in,
                              void* d_out, int out_size, void* d_ws, size_t ws_size,
                              hipStream_t stream){
    cfp x  = (cfp)d_in[0];
    const int* ei = (const int*)d_in[1];
    const int* esrc = ei;
    const int* edst = ei + EE;
    cfp W1=(cfp)d_in[3], b1=(cfp)d_in[4], W2=(cfp)d_in[5], b2=(cfp)d_in[6];
    cfp S =(cfp)d_in[7];
    cfp Wq=(cfp)d_in[8],  bq=(cfp)d_in[9],  Wk=(cfp)d_in[10], bk=(cfp)d_in[11];
    cfp Wv=(cfp)d_in[12], bv=(cfp)d_in[13], Wo=(cfp)d_in[14], bo=(cfp)d_in[15];
    cfp g0=(cfp)d_in[16], be0=(cfp)d_in[17], g1=(cfp)d_in[18], be1=(cfp)d_in[19];
    cfp Wl=(cfp)d_in[20], bl=(cfp)d_in[21], W3=(cfp)d_in[22], b3=(cfp)d_in[23];
    cfp W4=(cfp)d_in[24], b4=(cfp)d_in[25], W5=(cfp)d_in[26], b5=(cfp)d_in[27];

    char* wsb = (char*)d_ws;
    const size_t MB = 1048576;
    int*   deg    = (int*)  (wsb + 0);
    float* dinv   = (float*)(wsb + 81920);
    int*   rows   = (int*)  (wsb + 163840);
    int*   cursor = (int*)  (wsb + 245760);
    int*   col    = (int*)  (wsb + 327680);
    float* Qb     = (float*)(wsb + 2*MB);
    float* o1     = (float*)(wsb + 3*MB);    // also xl3 (fp32)
    float* o2     = (float*)(wsb + 4*MB);
    float* o3     = (float*)(wsb + 5*MB);
    float* xlb    = (float*)(wsb + 6*MB);
    float* zpart  = (float*)(wsb + 7*MB);                 // ZCH x NN fp32
    float* zinv   = (float*)(wsb + 10*MB);
    float* zdinv  = (float*)(wsb + 10*MB + 131072);
    unsigned short* Wts  = (unsigned short*)(wsb + 10*MB + 262144);
    unsigned short* Qbf  = (unsigned short*)(wsb + 11*MB);
    unsigned short* xlt3 = (unsigned short*)(wsb + 11*MB + 524288);  // [128 x KP] bf16
    unsigned short* xbf = (unsigned short*)(wsb + 12*MB); // also h3
    unsigned short* h1  = (unsigned short*)(wsb + 17*MB); // also h4
    unsigned short* h2  = (unsigned short*)(wsb + 22*MB);
    unsigned short* ybuf= (unsigned short*)(wsb + 27*MB);
    unsigned short* Kbf = (unsigned short*)(wsb + 32*MB);
    unsigned short* Vtz = (unsigned short*)(wsb + 37*MB);
    // time-aliased region 42..62 MiB: NB3 (Vd fp32, 9.8 MiB) -> part (16 MiB)
    float* NB3    = (float*)(wsb + 42*MB);
    float* part   = (float*)(wsb + 42*MB);
    unsigned short* E = (unsigned short*)(wsb + 62*MB);   // [ZCH][NN][512] bf16 = 78.1 MiB
    float* outp   = (float*)d_out;
    unsigned short* h3 = xbf;
    unsigned short* h4 = h1;

    (void)hipMemsetAsync(deg, 0, NN*sizeof(int), stream);
    (void)hipMemsetAsync(cursor, 0, NN*sizeof(int), stream);
    (void)hipMemsetAsync(xlt3, 0, 128*KP*sizeof(unsigned short), stream);  // pad cols must be finite

    // CSR build
    k_count<<<1250, 256, 0, stream>>>(edst, deg);
    k_dinv<<<79, 256, 0, stream>>>(deg, dinv);
    k_scan<<<1, 1024, 0, stream>>>(deg, rows);
    k_fill<<<1250, 256, 0, stream>>>(esrc, edst, rows, cursor, col);

    // weights -> bf16 transposed; x -> bf16
    conv_wT<<<dim3(2,2,7), 256, 0, stream>>>(W1, W2, Wk, Wv, W3, W4, W5, Wts);
    conv_bf16<<<2500, 256, 0, stream>>>(x, xbf, NN*32);
    unsigned short* W1t = Wts;
    unsigned short* W2t = Wts + 16384;
    unsigned short* Wkt = Wts + 2*16384;
    unsigned short* Wvt = Wts + 3*16384;
    unsigned short* W4t = Wts + 5*16384;
    unsigned short* W5t = Wts + 6*16384;

    const int GN = 313;   // ceil(NN/64)
    const int GK = 32;    // ceil(KK/64) == KP/64

    // GCN1
    tgemm<<<dim3(GN,2), 256, 0, stream>>>(xbf, NN, W1t, dinv, ybuf);
    gcn_agg_bf<<<5000, 256, 0, stream>>>(ybuf, dinv, rows, col, b1, h1, 1, 0);
    // GCN2 -> h2
    tgemm<<<dim3(GN,2), 256, 0, stream>>>(h1, NN, W2t, dinv, ybuf);
    gcn_agg_bf<<<5000, 256, 0, stream>>>(ybuf, dinv, rows, col, b2, h2, 1, 0);
    // Kd -> Kbf (bf16)
    tgemm<<<dim3(GN,2), 256, 0, stream>>>(h2, NN, Wkt, dinv, ybuf);
    gcn_agg_bf<<<5000, 256, 0, stream>>>(ybuf, dinv, rows, col, bk, Kbf, 0, 0);
    // Q = S@Wq + bq (fp32) -> Qbf
    gemm128<<<GK, 512, 0, stream>>>(S, Wq, Qb, KK, bq, nullptr, 0);
    conv_bf16<<<250, 256, 0, stream>>>(Qb, Qbf, KK*32);
    // E = exp(SCALE * Kd Q^T), z partials (block-row LDS buffering, 1KB-contiguous stores)
    s_gemm_exp<<<dim3(GN, ZCH), 256, 0, stream>>>(Kbf, Qbf, E, zpart);
    k_rcp32<<<79, 256, 0, stream>>>(zpart, dinv, zinv, zdinv);
    // Vd -> NB3 (fp32) -> Vtz (transposed bf16, pre-scaled by zinv[n])
    tgemm<<<dim3(GN,2), 256, 0, stream>>>(h2, NN, Wvt, dinv, ybuf);
    gcn_agg_bf<<<5000, 256, 0, stream>>>(ybuf, dinv, rows, col, bv, NB3, 0, 1);
    conv_bf16_T<<<dim3(GN, 2), 256, 0, stream>>>(NB3, Vtz, NN, NN, zinv);
    // attn partials (NB3 dead now; part aliases it)
    attn_gemm<<<dim3(GK, ZSPLIT), 256, 0, stream>>>(E, Vtz, part);
    // out = LN(sum(part) + Q)
    ln_ker<<<KK, 128, 0, stream>>>(part, ZSPLIT, Qb, g0, be0, o1);
    // o2 = o1 + relu(o1@Wo + bo)
    gemm128<<<GK, 512, 0, stream>>>(o1, Wo, o2, KK, bo, o1, 1);
    ln_ker<<<KK, 128, 0, stream>>>(o2, 1, nullptr, g1, be1, o3);
    // xl = o3@Wl + bl ; xl3 = xl @ W3  (GCN3 weight folded into the seed side)
    gemm128<<<GK, 512, 0, stream>>>(o3, Wl, xlb, KK, bl, nullptr, 0);
    gemm128<<<GK, 512, 0, stream>>>(xlb, W3, o1, KK, nullptr, nullptr, 0);
    conv_bf16_T<<<dim3(GK, 2), 256, 0, stream>>>(o1, xlt3, KK, KP, nullptr);
    // ybuf[n] = bf16(zinv*dinv*(E[n] @ xl3)) == GCN3 pre-agg activations (fused, no partials)
    xout_gemm<<<625, 256, 0, stream>>>(E, xlt3, zdinv, ybuf);
    // GCN3 aggregation
    gcn_agg_bf<<<5000, 256, 0, stream>>>(ybuf, dinv, rows, col, b3, h3, 1, 0);
    // GCN4
    tgemm<<<dim3(GN,2), 256, 0, stream>>>(h3, NN, W4t, dinv, ybuf);
    gcn_agg_bf<<<5000, 256, 0, stream>>>(ybuf, dinv, rows, col, b4, h4, 1, 0);
    // GCN5 -> d_out (fp32)
    tgemm<<<dim3(GN,2), 256, 0, stream>>>(h4, NN, W5t, dinv, ybuf);
    gcn_agg_bf<<<5000, 256, 0, stream>>>(ybuf, dinv, rows, col, b5, outp, 0, 1);
}

// Round 12
// 579.520 us; speedup vs baseline: 1.0581x; 1.0119x over previous
//
#include <hip/hip_runtime.h>

#define NN 20000
#define EE 320000
#define KK 2000
#define KP 2048          // padded K-dim of E (zeros in 2000..2047)
#define SCALE 0.08838834764831845f
#define ZSPLIT 16        // attn_gemm partial slices
#define ACHUNKS 625      // 20000 / 32
#define ZCH 4            // s_gemm_exp k-chunks (4 * 512 = 2048)

typedef const float* cfp;
typedef __attribute__((ext_vector_type(8))) short sh8;
typedef __attribute__((ext_vector_type(4))) float f32x4;

static __device__ __forceinline__ float4 ld4(const float* p){ return *reinterpret_cast<const float4*>(p); }
static __device__ __forceinline__ void st4(float* p, float4 v){ *reinterpret_cast<float4*>(p) = v; }

static __device__ __forceinline__ unsigned short f2bf(float f){
    unsigned int u = __float_as_uint(f);
    u = (u + 0x7FFFu + ((u >> 16) & 1u)) >> 16;
    return (unsigned short)u;
}
static __device__ __forceinline__ float bf2f(unsigned short h){
    return __uint_as_float(((unsigned int)h) << 16);
}
static __device__ __forceinline__ sh8 lds8(const unsigned short* p){ return *reinterpret_cast<const sh8*>(p); }

// async global->LDS, 16B per lane; LDS dest is wave-uniform base + lane*16
static __device__ __forceinline__ void stage16(const unsigned short* g, unsigned short* l){
    __builtin_amdgcn_global_load_lds(
        (const __attribute__((address_space(1))) unsigned int*)g,
        (__attribute__((address_space(3))) unsigned int*)l, 16, 0, 0);
}

// ---------------- CSR build ----------------
__global__ __launch_bounds__(256) void k_count(const int* dst, int* deg){
    int i = blockIdx.x*256 + threadIdx.x;
    if (i < EE) atomicAdd(&deg[dst[i]], 1);
}

__global__ __launch_bounds__(256) void k_dinv(const int* deg, float* dinv){
    int n = blockIdx.x*256 + threadIdx.x;
    if (n < NN) dinv[n] = rsqrtf((float)deg[n] + 1.0f);
}

__global__ __launch_bounds__(1024) void k_scan(const int* cnt, int* rows){
    __shared__ int part[1024];
    int t = threadIdx.x;
    int base = t*20;
    int s = 0;
    for (int i = 0; i < 20; ++i){ int idx = base+i; if (idx < NN) s += cnt[idx]; }
    part[t] = s; __syncthreads();
    for (int off = 1; off < 1024; off <<= 1){
        int v = (t >= off) ? part[t-off] : 0;
        __syncthreads();
        part[t] += v;
        __syncthreads();
    }
    int run = part[t] - s;   // exclusive
    for (int i = 0; i < 20; ++i){
        int idx = base+i;
        if (idx < NN){ rows[idx] = run; run += cnt[idx]; }
    }
    if (t == 0) rows[NN] = EE;
}

__global__ __launch_bounds__(256) void k_fill(const int* src, const int* dst, const int* rows,
                                              int* cursor, int* col){
    int i = blockIdx.x*256 + threadIdx.x;
    if (i < EE){
        int d = dst[i];
        int pos = rows[d] + atomicAdd(&cursor[d], 1);
        col[pos] = src[i];
    }
}

// ---------------- weight transpose+convert ----------------
__global__ __launch_bounds__(256) void conv_wT(cfp w0, cfp w1, cfp w2, cfp w3, cfp w4, cfp w5, cfp w6,
                                               unsigned short* wts){
    const float* in;
    switch (blockIdx.z){
        case 0: in = w0; break; case 1: in = w1; break; case 2: in = w2; break;
        case 3: in = w3; break; case 4: in = w4; break; case 5: in = w5; break;
        default: in = w6; break;
    }
    unsigned short* out = wts + (size_t)blockIdx.z*16384;
    __shared__ float t[64][65];
    int r0 = blockIdx.x*64, c0 = blockIdx.y*64;
    int tid = threadIdx.x;
    for (int i = tid; i < 64*16; i += 256){
        int r = i >> 4, c4 = (i & 15) * 4;
        float4 v = ld4(in + (size_t)(r0+r)*128 + c0 + c4);
        t[r][c4+0]=v.x; t[r][c4+1]=v.y; t[r][c4+2]=v.z; t[r][c4+3]=v.w;
    }
    __syncthreads();
    for (int i = tid; i < 64*16; i += 256){
        int c = i >> 4, r4 = (i & 15) * 4;
        ushort4 o;
        o.x = f2bf(t[r4+0][c]); o.y = f2bf(t[r4+1][c]);
        o.z = f2bf(t[r4+2][c]); o.w = f2bf(t[r4+3][c]);
        *reinterpret_cast<ushort4*>(out + (size_t)(c0+c)*128 + r0 + r4) = o;
    }
}

// ---------------- fp32 GEMM (KK-sized only) ----------------
__global__ __launch_bounds__(512) void gemm128(const float* __restrict__ A, const float* __restrict__ Wm,
                                               float* __restrict__ C, int M,
                                               const float* bias, const float* resid, int relu){
    __shared__ __align__(16) float Ws[128*132];
    __shared__ float As[64*129];
    int tid = threadIdx.x;
    int r0 = blockIdx.x*64;
    for (int i = tid; i < 128*32; i += 512){
        int r = i >> 5, c4 = (i & 31) * 4;
        float4 v = ld4(Wm + r*128 + c4);
        st4(&Ws[r*132 + c4], v);
    }
    for (int i = tid; i < 64*32; i += 512){
        int r = i >> 5, c4 = (i & 31) * 4;
        float4 v = (r0 + r < M) ? ld4(A + (size_t)(r0+r)*128 + c4) : make_float4(0,0,0,0);
        As[r*129 + c4+0] = v.x; As[r*129 + c4+1] = v.y;
        As[r*129 + c4+2] = v.z; As[r*129 + c4+3] = v.w;
    }
    __syncthreads();
    int a = tid >> 5;
    int b = tid & 31;
    float acc[4][4] = {};
    #pragma unroll 4
    for (int d = 0; d < 128; ++d){
        float4 w = ld4(&Ws[d*132 + 4*b]);
        float wv[4] = {w.x, w.y, w.z, w.w};
        float av[4];
        #pragma unroll
        for (int i = 0; i < 4; ++i) av[i] = As[(4*a+i)*129 + d];
        #pragma unroll
        for (int i = 0; i < 4; ++i)
            #pragma unroll
            for (int j = 0; j < 4; ++j)
                acc[i][j] += av[i]*wv[j];
    }
    int cc = 4*b;
    #pragma unroll
    for (int i = 0; i < 4; ++i){
        int r = r0 + 4*a + i;
        if (r < M){
            float v[4];
            #pragma unroll
            for (int j = 0; j < 4; ++j) v[j] = acc[i][j];
            if (bias){
                #pragma unroll
                for (int j = 0; j < 4; ++j) v[j] += bias[cc+j];
            }
            if (relu){
                #pragma unroll
                for (int j = 0; j < 4; ++j) v[j] = fmaxf(v[j], 0.f);
            }
            if (resid){
                float4 rv = ld4(resid + (size_t)r*128 + cc);
                v[0]+=rv.x; v[1]+=rv.y; v[2]+=rv.z; v[3]+=rv.w;
            }
            st4(C + (size_t)r*128 + cc, make_float4(v[0],v[1],v[2],v[3]));
        }
    }
}

// ---------------- bf16 MFMA GEMM: C[M x 128] = (A@W)*rscale, bf16 out ----------------
__global__ __launch_bounds__(256) void tgemm(const unsigned short* __restrict__ A, int M,
                                             const unsigned short* __restrict__ Wt,
                                             const float* __restrict__ rscale,
                                             unsigned short* __restrict__ C){
    int tid = threadIdx.x;
    int wave = tid >> 6, lane = tid & 63;
    int wm = wave >> 1, wn = wave & 1;
    int m_base = blockIdx.x*64 + wm*32;
    int n_base = blockIdx.y*64 + wn*32;
    int l15 = lane & 15;
    int roff = (lane >> 4) * 8;
    const unsigned short* ap0 = A + (size_t)(m_base + l15)*128 + roff;
    const unsigned short* ap1 = ap0 + 16*128;
    const unsigned short* b0p = Wt + (size_t)(n_base + l15)*128 + roff;
    const unsigned short* b1p = b0p + 16*128;
    f32x4 acc00 = (f32x4)0.f, acc01 = (f32x4)0.f, acc10 = (f32x4)0.f, acc11 = (f32x4)0.f;
    #pragma unroll
    for (int r = 0; r < 128; r += 32){
        sh8 a0 = lds8(ap0 + r);
        sh8 a1 = lds8(ap1 + r);
        sh8 b0 = lds8(b0p + r);
        sh8 b1 = lds8(b1p + r);
        acc00 = __builtin_amdgcn_mfma_f32_16x16x32_bf16(a0, b0, acc00, 0, 0, 0);
        acc01 = __builtin_amdgcn_mfma_f32_16x16x32_bf16(a0, b1, acc01, 0, 0, 0);
        acc10 = __builtin_amdgcn_mfma_f32_16x16x32_bf16(a1, b0, acc10, 0, 0, 0);
        acc11 = __builtin_amdgcn_mfma_f32_16x16x32_bf16(a1, b1, acc11, 0, 0, 0);
    }
    int rq = (lane >> 4) * 4;
    f32x4 accs[2][2] = {{acc00, acc01},{acc10, acc11}};
    #pragma unroll
    for (int mi = 0; mi < 2; ++mi){
        #pragma unroll
        for (int ni = 0; ni < 2; ++ni){
            f32x4 a = accs[mi][ni];
            int gn = n_base + ni*16 + l15;
            #pragma unroll
            for (int reg = 0; reg < 4; ++reg){
                int gm = m_base + mi*16 + rq + reg;
                if (gm < M) C[(size_t)gm*128 + gn] = f2bf(a[reg] * (rscale ? rscale[gm] : 1.f));
            }
        }
    }
}

// ---------------- GCN aggregation (bf16 in, fp32 accumulate), neighbor unroll 8 ----------------
__global__ __launch_bounds__(256) void gcn_agg_bf(const unsigned short* __restrict__ y, const float* __restrict__ dinv,
                                                  const int* __restrict__ rows, const int* __restrict__ col,
                                                  const float* __restrict__ bias, void* __restrict__ outv,
                                                  int relu, int out_fp32){
    int wid = (int)((blockIdx.x*256 + threadIdx.x) >> 6);
    int lane = threadIdx.x & 63;
    if (wid >= NN) return;
    int f = lane*2;
    ushort2 u = *reinterpret_cast<const ushort2*>(y + (size_t)wid*128 + f);
    float ax = bf2f(u.x), ay = bf2f(u.y);
    int s = rows[wid], e = rows[wid+1];
    int j = s;
    int e8 = s + ((e - s) & ~7);
    for (; j < e8; j += 8){
        ushort2 v[8];
        #pragma unroll
        for (int q = 0; q < 8; ++q){
            int c = col[j+q];
            v[q] = *reinterpret_cast<const ushort2*>(y + (size_t)c*128 + f);
        }
        #pragma unroll
        for (int q = 0; q < 8; ++q){ ax += bf2f(v[q].x); ay += bf2f(v[q].y); }
    }
    for (; j < e; ++j){
        int c0 = col[j];
        ushort2 v0 = *reinterpret_cast<const ushort2*>(y + (size_t)c0*128 + f);
        ax += bf2f(v0.x); ay += bf2f(v0.y);
    }
    float dn = dinv[wid];
    float ox = ax*dn + bias[f];
    float oy = ay*dn + bias[f+1];
    if (relu){ ox = fmaxf(ox, 0.f); oy = fmaxf(oy, 0.f); }
    if (out_fp32){
        *reinterpret_cast<float2*>((float*)outv + (size_t)wid*128 + f) = make_float2(ox, oy);
    } else {
        ushort2 o; o.x = f2bf(ox); o.y = f2bf(oy);
        *reinterpret_cast<ushort2*>((unsigned short*)outv + (size_t)wid*128 + f) = o;
    }
}

// ---------------- convert fp32 -> bf16 ----------------
__global__ __launch_bounds__(256) void conv_bf16(const float* __restrict__ in, unsigned short* __restrict__ out, int n4){
    int i = blockIdx.x*256 + threadIdx.x;
    if (i < n4){
        float4 v = ld4(in + (size_t)i*4);
        ushort4 o;
        o.x = f2bf(v.x); o.y = f2bf(v.y); o.z = f2bf(v.z); o.w = f2bf(v.w);
        *reinterpret_cast<ushort4*>(out + (size_t)i*4) = o;
    }
}

// ---------------- convert + transpose (+ optional per-source-row scale) ----------------
__global__ __launch_bounds__(256) void conv_bf16_T(const float* __restrict__ in, unsigned short* __restrict__ out,
                                                   int M, int ldout, const float* __restrict__ rscale){
    __shared__ float t[64][65];
    int r0 = blockIdx.x*64, c0 = blockIdx.y*64;
    int tid = threadIdx.x;
    for (int i = tid; i < 64*16; i += 256){
        int r = i >> 4, c4 = (i & 15) * 4;
        float4 v = (r0 + r < M) ? ld4(in + (size_t)(r0+r)*128 + c0 + c4) : make_float4(0,0,0,0);
        if (rscale && r0 + r < M){
            float sc = rscale[r0 + r];
            v.x *= sc; v.y *= sc; v.z *= sc; v.w *= sc;
        }
        t[r][c4+0]=v.x; t[r][c4+1]=v.y; t[r][c4+2]=v.z; t[r][c4+3]=v.w;
    }
    __syncthreads();
    for (int i = tid; i < 64*16; i += 256){
        int c = i >> 4, r4 = (i & 15) * 4;
        if (r0 + r4 < M){
            ushort4 o;
            o.x = f2bf(t[r4+0][c]); o.y = f2bf(t[r4+1][c]);
            o.z = f2bf(t[r4+2][c]); o.w = f2bf(t[r4+3][c]);
            *reinterpret_cast<ushort4*>(out + (size_t)(c0+c)*ldout + r0 + r4) = o;
        }
    }
}

// ---------------- z reduction: zinv[n] = 1/sum, zdinv[n] = zinv[n]*dinv[n] ----------------
__global__ __launch_bounds__(256) void k_rcp32(const float* __restrict__ zp, const float* __restrict__ dinv,
                                               float* __restrict__ zinv, float* __restrict__ zdinv){
    int n = blockIdx.x*256 + threadIdx.x;
    if (n < NN){
        float s = 0.f;
        #pragma unroll
        for (int y = 0; y < ZCH; ++y) s += zp[(size_t)y*NN + n];
        float zi = 1.f / s;
        zinv[n] = zi;
        zdinv[n] = zi * dinv[n];
    }
}

// ---------------- S-GEMM + exp + z-partials ----------------
// grid (313 n-blocks, ZCH k-chunks). Wave-private quadrant staging: each wave owns a
// 32x32 quadrant end-to-end (MFMA -> exp -> private LDS -> global), NO barriers in the
// k-loop (per-wave in-order DS pipe orders the LDS write->read). Waves slip freely.
__global__ __launch_bounds__(256) void s_gemm_exp(const unsigned short* __restrict__ Kb,
                                                  const unsigned short* __restrict__ Qb2,
                                                  unsigned short* __restrict__ E, float* __restrict__ zpart){
    __shared__ unsigned short Es[4][32*36];   // per-wave private quadrant, pad 36
    __shared__ float zsh[2][64];
    int tid = threadIdx.x;
    int wave = tid >> 6, lane = tid & 63;
    int wm = wave >> 1, wn = wave & 1;
    int n_blk = blockIdx.x*64;
    int k_base = blockIdx.y*512;
    int l15 = lane & 15;
    int h = lane >> 4;
    int roff = h * 8;
    int rq = h * 4;
    unsigned short* myEs = Es[wave];
    // Kd fragments (reused across all 8 k-blocks)
    const unsigned short* ap0 = Kb + (size_t)(n_blk + wm*32 + l15)*128 + roff;
    const unsigned short* ap1 = ap0 + 16*128;
    sh8 a0[4], a1[4];
    #pragma unroll
    for (int r = 0; r < 4; ++r){ a0[r] = lds8(ap0 + r*32); a1[r] = lds8(ap1 + r*32); }
    // Q fragments, double buffered
    const unsigned short* qbase = Qb2 + (size_t)(k_base + wn*32 + l15)*128 + roff;
    sh8 q0[4], q1[4];
    #pragma unroll
    for (int r = 0; r < 4; ++r){ q0[r] = lds8(qbase + r*32); q1[r] = lds8(qbase + 16*128 + r*32); }
    float zacc[2][4] = {{0.f,0.f,0.f,0.f},{0.f,0.f,0.f,0.f}};
    for (int kb = 0; kb < 8; ++kb){
        sh8 n0[4], n1[4];
        if (kb < 7){
            const unsigned short* qn = qbase + (size_t)(kb+1)*64*128;
            #pragma unroll
            for (int r = 0; r < 4; ++r){ n0[r] = lds8(qn + r*32); n1[r] = lds8(qn + 16*128 + r*32); }
        } else {
            #pragma unroll
            for (int r = 0; r < 4; ++r){ n0[r] = (sh8)0; n1[r] = (sh8)0; }
        }
        f32x4 acc00 = (f32x4)0.f, acc01 = (f32x4)0.f, acc10 = (f32x4)0.f, acc11 = (f32x4)0.f;
        #pragma unroll
        for (int r = 0; r < 4; ++r){
            acc00 = __builtin_amdgcn_mfma_f32_16x16x32_bf16(a0[r], q0[r], acc00, 0, 0, 0);
            acc01 = __builtin_amdgcn_mfma_f32_16x16x32_bf16(a0[r], q1[r], acc01, 0, 0, 0);
            acc10 = __builtin_amdgcn_mfma_f32_16x16x32_bf16(a1[r], q0[r], acc10, 0, 0, 0);
            acc11 = __builtin_amdgcn_mfma_f32_16x16x32_bf16(a1[r], q1[r], acc11, 0, 0, 0);
        }
        int kcol = k_base + kb*64;
        f32x4 accs[2][2] = {{acc00, acc01},{acc10, acc11}};
        // exp + write own quadrant to private LDS (rows 0..31 = quadrant rows, cols 0..31)
        #pragma unroll
        for (int mi = 0; mi < 2; ++mi){
            #pragma unroll
            for (int ni = 0; ni < 2; ++ni){
                f32x4 a = accs[mi][ni];
                bool kv = (kcol + wn*32 + ni*16 + l15) < KK;
                #pragma unroll
                for (int reg = 0; reg < 4; ++reg){
                    float e = kv ? __expf(a[reg]*SCALE) : 0.f;
                    myEs[(mi*16 + rq + reg)*36 + ni*16 + l15] = f2bf(e);
                    zacc[mi][reg] += e;
                }
            }
        }
        // read back own quadrant (b128) and store to global (64B row segments)
        #pragma unroll
        for (int it = 0; it < 2; ++it){
            int r = it*16 + (lane >> 2);
            int q4 = (lane & 3) * 8;
            sh8 v = lds8(myEs + r*36 + q4);
            int gr = n_blk + wm*32 + r;
            if (gr < NN)
                *reinterpret_cast<sh8*>(E + (size_t)gr*KP + kcol + wn*32 + q4) = v;
        }
        #pragma unroll
        for (int r = 0; r < 4; ++r){ q0[r] = n0[r]; q1[r] = n1[r]; }
    }
    // z reduction: sum over the 16 lanes of each l15-group (covers this wave's 32 cols)
    #pragma unroll
    for (int mi = 0; mi < 2; ++mi){
        #pragma unroll
        for (int reg = 0; reg < 4; ++reg){
            float v = zacc[mi][reg];
            v += __shfl_xor(v, 1);
            v += __shfl_xor(v, 2);
            v += __shfl_xor(v, 4);
            v += __shfl_xor(v, 8);
            zacc[mi][reg] = v;
        }
    }
    if (l15 == 0){
        #pragma unroll
        for (int mi = 0; mi < 2; ++mi)
            #pragma unroll
            for (int reg = 0; reg < 4; ++reg)
                zsh[wn][wm*32 + mi*16 + h*4 + reg] = zacc[mi][reg];
    }
    __syncthreads();
    if (tid < 64){
        int n = n_blk + tid;
        if (n < NN) zpart[(size_t)blockIdx.y*NN + n] = zsh[0][tid] + zsh[1][tid];
    }
}

// ---------------- attn GEMM partials with next-chunk prefetch ----------------
__global__ __launch_bounds__(256) void attn_gemm(const unsigned short* __restrict__ E,
                                                 const unsigned short* __restrict__ Vt,
                                                 float* __restrict__ part){
    __shared__ unsigned short As[64*36];
    int tid = threadIdx.x;
    int wave = tid >> 6, lane = tid & 63;
    int kk0 = blockIdx.x*64;
    int per = (ACHUNKS + ZSPLIT - 1) / ZSPLIT;
    int c0 = blockIdx.y*per;
    int c1 = min(ACHUNKS, c0 + per);
    int l15 = lane & 15;
    int q8 = (lane >> 4) * 8;
    int d0 = wave*32;
    int n_l = tid & 31;
    int k8 = (tid >> 5) * 8;
    f32x4 acc[4][2];
    #pragma unroll
    for (int g = 0; g < 4; ++g){ acc[g][0] = (f32x4)0.f; acc[g][1] = (f32x4)0.f; }
    const unsigned short* ebase = E + (size_t)n_l*KP + kk0 + k8;
    const unsigned short* vb0p = Vt + (size_t)(d0 + l15)*NN + q8;
    const unsigned short* vb1p = vb0p + (size_t)16*NN;
    sh8 etmp = lds8(ebase + (size_t)c0*32*KP);
    sh8 vb0 = lds8(vb0p + c0*32);
    sh8 vb1 = lds8(vb1p + c0*32);
    for (int ch = c0; ch < c1; ++ch){
        unsigned short tmp[8];
        *reinterpret_cast<sh8*>(tmp) = etmp;
        #pragma unroll
        for (int j = 0; j < 8; ++j) As[(k8 + j)*36 + n_l] = tmp[j];
        __syncthreads();
        sh8 etn = (sh8)0, vbn0 = (sh8)0, vbn1 = (sh8)0;
        if (ch + 1 < c1){
            etn  = lds8(ebase + (size_t)(ch+1)*32*KP);
            vbn0 = lds8(vb0p + (ch+1)*32);
            vbn1 = lds8(vb1p + (ch+1)*32);
        }
        #pragma unroll
        for (int g = 0; g < 4; ++g){
            const unsigned short* ap = &As[(g*16 + l15)*36 + q8];
            union { struct { ushort4 lo, hi; } u; sh8 v; } af;
            af.u.lo = *reinterpret_cast<const ushort4*>(ap);
            af.u.hi = *reinterpret_cast<const ushort4*>(ap + 4);
            acc[g][0] = __builtin_amdgcn_mfma_f32_16x16x32_bf16(af.v, vb0, acc[g][0], 0, 0, 0);
            acc[g][1] = __builtin_amdgcn_mfma_f32_16x16x32_bf16(af.v, vb1, acc[g][1], 0, 0, 0);
        }
        __syncthreads();
        etmp = etn; vb0 = vbn0; vb1 = vbn1;
    }
    float* pbase = part + (size_t)blockIdx.y*KK*128;
    int rq = (lane >> 4) * 4;
    #pragma unroll
    for (int g = 0; g < 4; ++g){
        #pragma unroll
        for (int ni = 0; ni < 2; ++ni){
            int d = d0 + ni*16 + l15;
            #pragma unroll
            for (int reg = 0; reg < 4; ++reg){
                int kk = kk0 + g*16 + rq + reg;
                if (kk < KK) pbase[(size_t)kk*128 + d] = acc[g][ni][reg];
            }
        }
    }
}

// ---------------- xout GEMM: full K=2048 sweep, LDS-staged E (swizzled), bf16 out fused with zdinv ----------------
// grid 625 blocks x 256 threads. Block: E rows [m_base, m_base+32), all 128 d-cols.
// E tile (32 rows x 128 k = 8KB) staged via global_load_lds, double-buffered.
// LDS layout: linear [row][kb], swizzle: LDS[row][kb] = E[row][kb ^ ((row&15)<<4)]
// (swizzle pre-applied to the GLOBAL source addr; read applies same XOR to the FULL in-row byte offset).
__global__ __launch_bounds__(256) void xout_gemm(const unsigned short* __restrict__ E,
                                                 const unsigned short* __restrict__ B,
                                                 const float* __restrict__ zdinv,
                                                 unsigned short* __restrict__ out){
    __shared__ __align__(16) unsigned short ebuf[2][4096];   // 2 x 8 KB
    int tid = threadIdx.x;
    int wave = tid >> 6, lane = tid & 63;
    int l15 = lane & 15;
    int h = lane >> 4;
    int m_base = blockIdx.x*32;
    int srow0 = wave*4 + h;            // issue 0 row (0..15)
    int skb0  = (l15*16) ^ ((srow0 & 15) << 4);
    int srow1 = 16 + srow0;            // issue 1 row (16..31)
    int skb1  = (l15*16) ^ ((srow1 & 15) << 4);
    const unsigned short* g0 = E + (size_t)(m_base + srow0)*KP + (skb0 >> 1);
    const unsigned short* g1 = E + (size_t)(m_base + srow1)*KP + (skb1 >> 1);
    unsigned short* l0 = &ebuf[0][wave*512];          // + issue*2048 ushorts
    unsigned short* l1 = &ebuf[1][wave*512];
    const unsigned short* bp0 = B + (size_t)(wave*32 + l15)*KP + h*8;
    const unsigned short* bp1 = bp0 + (size_t)16*KP;
    int rswz = l15 << 4;

    f32x4 acc[2][2];
    #pragma unroll
    for (int mi = 0; mi < 2; ++mi)
        #pragma unroll
        for (int ni = 0; ni < 2; ++ni) acc[mi][ni] = (f32x4)0.f;

    // prologue: stage tile 0, load B tile 0
    stage16(g0, l0);
    stage16(g1, l0 + 2048);
    sh8 b0[4], b1[4];
    #pragma unroll
    for (int s = 0; s < 4; ++s){ b0[s] = lds8(bp0 + s*32); b1[s] = lds8(bp1 + s*32); }
    __syncthreads();

    for (int t = 0; t < 16; ++t){
        if (t < 15){
            const unsigned short* ng0 = g0 + (t+1)*128;
            const unsigned short* ng1 = g1 + (t+1)*128;
            unsigned short* nl = (t & 1) ? l0 : l1;
            stage16(ng0, nl);
            stage16(ng1, nl + 2048);
        }
        sh8 nb0[4], nb1[4];
        if (t < 15){
            #pragma unroll
            for (int s = 0; s < 4; ++s){
                nb0[s] = lds8(bp0 + (t+1)*128 + s*32);
                nb1[s] = lds8(bp1 + (t+1)*128 + s*32);
            }
        } else {
            #pragma unroll
            for (int s = 0; s < 4; ++s){ nb0[s] = (sh8)0; nb1[s] = (sh8)0; }
        }
        const unsigned short* eb = (t & 1) ? ebuf[1] : ebuf[0];
        #pragma unroll
        for (int s = 0; s < 4; ++s){
            int ko = ((h*16 + s*64) ^ rswz) >> 1;     // ushort offset within row, stays < 128
            sh8 a0 = lds8(eb + l15*128 + ko);
            sh8 a1 = lds8(eb + (16 + l15)*128 + ko);
            acc[0][0] = __builtin_amdgcn_mfma_f32_16x16x32_bf16(a0, b0[s], acc[0][0], 0, 0, 0);
            acc[0][1] = __builtin_amdgcn_mfma_f32_16x16x32_bf16(a0, b1[s], acc[0][1], 0, 0, 0);
            acc[1][0] = __builtin_amdgcn_mfma_f32_16x16x32_bf16(a1, b0[s], acc[1][0], 0, 0, 0);
            acc[1][1] = __builtin_amdgcn_mfma_f32_16x16x32_bf16(a1, b1[s], acc[1][1], 0, 0, 0);
        }
        __syncthreads();
        #pragma unroll
        for (int s = 0; s < 4; ++s){ b0[s] = nb0[s]; b1[s] = nb1[s]; }
    }

    int rq = h*4;
    #pragma unroll
    for (int mi = 0; mi < 2; ++mi){
        #pragma unroll
        for (int ni = 0; ni < 2; ++ni){
            f32x4 a = acc[mi][ni];
            int d = wave*32 + ni*16 + l15;
            #pragma unroll
            for (int reg = 0; reg < 4; ++reg){
                int gm = m_base + mi*16 + rq + reg;
                out[(size_t)gm*128 + d] = f2bf(a[reg] * zdinv[gm]);
            }
        }
    }
}

// ---------------- LayerNorm over D=128 (with partial-sum input) ----------------
__global__ __launch_bounds__(128) void ln_ker(const float* __restrict__ in, int nparts,
                                              const float* __restrict__ resid,
                                              const float* __restrict__ g, const float* __restrict__ be,
                                              float* __restrict__ out){
    __shared__ float rs[128], rq[128];
    int r = blockIdx.x, t = threadIdx.x;
    float v = 0.f;
    for (int p = 0; p < nparts; ++p) v += in[(size_t)p*KK*128 + r*128 + t];
    if (resid) v += resid[r*128 + t];
    rs[t] = v; rq[t] = v*v;
    __syncthreads();
    for (int off = 64; off > 0; off >>= 1){
        if (t < off){ rs[t] += rs[t+off]; rq[t] += rq[t+off]; }
        __syncthreads();
    }
    float mean = rs[0]*(1.f/128.f);
    float var = rq[0]*(1.f/128.f) - mean*mean;
    out[r*128 + t] = (v - mean)*rsqrtf(var + 1e-5f)*g[t] + be[t];
}

// ---------------- launcher ----------------
extern "C" void kernel_launch(void* const* d_in, const int* in_sizes, int n_in,
                              void* d_out, int out_size, void* d_ws, size_t ws_size,
                              hipStream_t stream){
    cfp x  = (cfp)d_in[0];
    const int* ei = (const int*)d_in[1];
    const int* esrc = ei;
    const int* edst = ei + EE;
    cfp W1=(cfp)d_in[3], b1=(cfp)d_in[4], W2=(cfp)d_in[5], b2=(cfp)d_in[6];
    cfp S =(cfp)d_in[7];
    cfp Wq=(cfp)d_in[8],  bq=(cfp)d_in[9],  Wk=(cfp)d_in[10], bk=(cfp)d_in[11];
    cfp Wv=(cfp)d_in[12], bv=(cfp)d_in[13], Wo=(cfp)d_in[14], bo=(cfp)d_in[15];
    cfp g0=(cfp)d_in[16], be0=(cfp)d_in[17], g1=(cfp)d_in[18], be1=(cfp)d_in[19];
    cfp Wl=(cfp)d_in[20], bl=(cfp)d_in[21], W3=(cfp)d_in[22], b3=(cfp)d_in[23];
    cfp W4=(cfp)d_in[24], b4=(cfp)d_in[25], W5=(cfp)d_in[26], b5=(cfp)d_in[27];

    char* wsb = (char*)d_ws;
    const size_t MB = 1048576;
    int*   deg    = (int*)  (wsb + 0);
    float* dinv   = (float*)(wsb + 81920);
    int*   rows   = (int*)  (wsb + 163840);
    int*   cursor = (int*)  (wsb + 245760);
    int*   col    = (int*)  (wsb + 327680);
    float* Qb     = (float*)(wsb + 2*MB);
    float* o1     = (float*)(wsb + 3*MB);    // also xl3 (fp32)
    float* o2     = (float*)(wsb + 4*MB);
    float* o3     = (float*)(wsb + 5*MB);
    float* xlb    = (float*)(wsb + 6*MB);
    float* zpart  = (float*)(wsb + 7*MB);                 // ZCH x NN fp32
    float* zinv   = (float*)(wsb + 10*MB);
    float* zdinv  = (float*)(wsb + 10*MB + 131072);
    unsigned short* Wts  = (unsigned short*)(wsb + 10*MB + 262144);
    unsigned short* Qbf  = (unsigned short*)(wsb + 11*MB);
    unsigned short* xlt3 = (unsigned short*)(wsb + 11*MB + 524288);  // [128 x KP] bf16
    unsigned short* xbf = (unsigned short*)(wsb + 12*MB); // also h3
    unsigned short* h1  = (unsigned short*)(wsb + 17*MB); // also h4
    unsigned short* h2  = (unsigned short*)(wsb + 22*MB);
    unsigned short* ybuf= (unsigned short*)(wsb + 27*MB);
    unsigned short* Kbf = (unsigned short*)(wsb + 32*MB);
    unsigned short* Vtz = (unsigned short*)(wsb + 37*MB);
    // time-aliased region 42..62 MiB: NB3 (Vd fp32, 9.8 MiB) -> part (16 MiB)
    float* NB3    = (float*)(wsb + 42*MB);
    float* part   = (float*)(wsb + 42*MB);
    unsigned short* E = (unsigned short*)(wsb + 62*MB);   // [NN x KP] bf16 = 78.1 MiB -> ends ~140.1 MiB
    float* outp   = (float*)d_out;
    unsigned short* h3 = xbf;
    unsigned short* h4 = h1;

    (void)hipMemsetAsync(deg, 0, NN*sizeof(int), stream);
    (void)hipMemsetAsync(cursor, 0, NN*sizeof(int), stream);
    (void)hipMemsetAsync(xlt3, 0, 128*KP*sizeof(unsigned short), stream);  // pad cols must be finite

    // CSR build
    k_count<<<1250, 256, 0, stream>>>(edst, deg);
    k_dinv<<<79, 256, 0, stream>>>(deg, dinv);
    k_scan<<<1, 1024, 0, stream>>>(deg, rows);
    k_fill<<<1250, 256, 0, stream>>>(esrc, edst, rows, cursor, col);

    // weights -> bf16 transposed; x -> bf16
    conv_wT<<<dim3(2,2,7), 256, 0, stream>>>(W1, W2, Wk, Wv, W3, W4, W5, Wts);
    conv_bf16<<<2500, 256, 0, stream>>>(x, xbf, NN*32);
    unsigned short* W1t = Wts;
    unsigned short* W2t = Wts + 16384;
    unsigned short* Wkt = Wts + 2*16384;
    unsigned short* Wvt = Wts + 3*16384;
    unsigned short* W4t = Wts + 5*16384;
    unsigned short* W5t = Wts + 6*16384;

    const int GN = 313;   // ceil(NN/64)
    const int GK = 32;    // ceil(KK/64) == KP/64

    // GCN1
    tgemm<<<dim3(GN,2), 256, 0, stream>>>(xbf, NN, W1t, dinv, ybuf);
    gcn_agg_bf<<<5000, 256, 0, stream>>>(ybuf, dinv, rows, col, b1, h1, 1, 0);
    // GCN2 -> h2
    tgemm<<<dim3(GN,2), 256, 0, stream>>>(h1, NN, W2t, dinv, ybuf);
    gcn_agg_bf<<<5000, 256, 0, stream>>>(ybuf, dinv, rows, col, b2, h2, 1, 0);
    // Kd -> Kbf (bf16)
    tgemm<<<dim3(GN,2), 256, 0, stream>>>(h2, NN, Wkt, dinv, ybuf);
    gcn_agg_bf<<<5000, 256, 0, stream>>>(ybuf, dinv, rows, col, bk, Kbf, 0, 0);
    // Q = S@Wq + bq (fp32) -> Qbf
    gemm128<<<GK, 512, 0, stream>>>(S, Wq, Qb, KK, bq, nullptr, 0);
    conv_bf16<<<250, 256, 0, stream>>>(Qb, Qbf, KK*32);
    // E = exp(SCALE * Kd Q^T), z partials (reg-cached Kd, 4 k-chunks, wave-private staging)
    s_gemm_exp<<<dim3(GN, ZCH), 256, 0, stream>>>(Kbf, Qbf, E, zpart);
    k_rcp32<<<79, 256, 0, stream>>>(zpart, dinv, zinv, zdinv);
    // Vd -> NB3 (fp32) -> Vtz (transposed bf16, pre-scaled by zinv[n])
    tgemm<<<dim3(GN,2), 256, 0, stream>>>(h2, NN, Wvt, dinv, ybuf);
    gcn_agg_bf<<<5000, 256, 0, stream>>>(ybuf, dinv, rows, col, bv, NB3, 0, 1);
    conv_bf16_T<<<dim3(GN, 2), 256, 0, stream>>>(NB3, Vtz, NN, NN, zinv);
    // attn partials (NB3 dead now; part aliases it)
    attn_gemm<<<dim3(GK, ZSPLIT), 256, 0, stream>>>(E, Vtz, part);
    // out = LN(sum(part) + Q)
    ln_ker<<<KK, 128, 0, stream>>>(part, ZSPLIT, Qb, g0, be0, o1);
    // o2 = o1 + relu(o1@Wo + bo)
    gemm128<<<GK, 512, 0, stream>>>(o1, Wo, o2, KK, bo, o1, 1);
    ln_ker<<<KK, 128, 0, stream>>>(o2, 1, nullptr, g1, be1, o3);
    // xl = o3@Wl + bl ; xl3 = xl @ W3  (GCN3 weight folded into the seed side)
    gemm128<<<GK, 512, 0, stream>>>(o3, Wl, xlb, KK, bl, nullptr, 0);
    gemm128<<<GK, 512, 0, stream>>>(xlb, W3, o1, KK, nullptr, nullptr, 0);
    conv_bf16_T<<<dim3(GK, 2), 256, 0, stream>>>(o1, xlt3, KK, KP, nullptr);
    // ybuf[n] = bf16(zinv*dinv*(E[n] @ xl3)) == GCN3 pre-agg activations (fused, no partials)
    xout_gemm<<<625, 256, 0, stream>>>(E, xlt3, zdinv, ybuf);
    // GCN3 aggregation
    gcn_agg_bf<<<5000, 256, 0, stream>>>(ybuf, dinv, rows, col, b3, h3, 1, 0);
    // GCN4
    tgemm<<<dim3(GN,2), 256, 0, stream>>>(h3, NN, W4t, dinv, ybuf);
    gcn_agg_bf<<<5000, 256, 0, stream>>>(ybuf, dinv, rows, col, b4, h4, 1, 0);
    // GCN5 -> d_out (fp32)
    tgemm<<<dim3(GN,2), 256, 0, stream>>>(h4, NN, W5t, dinv, ybuf);
    gcn_agg_bf<<<5000, 256, 0, stream>>>(ybuf, dinv, rows, col, b5, outp, 0, 1);
}

// Round 13
// 560.780 us; speedup vs baseline: 1.0935x; 1.0334x over previous
//
#include <hip/hip_runtime.h>

#define NN 20000
#define EE 320000
#define KK 2000
#define KP 2048          // padded K-dim of E (zeros in 2000..2047)
#define SCALE 0.08838834764831845f
#define ZSPLIT 16        // attn_gemm partial slices
#define ACHUNKS 625      // 20000 / 32
#define ZCH 4            // s_gemm_exp k-chunks (4 * 512 = 2048)

typedef const float* cfp;
typedef __attribute__((ext_vector_type(8))) short sh8;
typedef __attribute__((ext_vector_type(4))) float f32x4;

static __device__ __forceinline__ float4 ld4(const float* p){ return *reinterpret_cast<const float4*>(p); }
static __device__ __forceinline__ void st4(float* p, float4 v){ *reinterpret_cast<float4*>(p) = v; }

static __device__ __forceinline__ unsigned short f2bf(float f){
    unsigned int u = __float_as_uint(f);
    u = (u + 0x7FFFu + ((u >> 16) & 1u)) >> 16;
    return (unsigned short)u;
}
static __device__ __forceinline__ float bf2f(unsigned short h){
    return __uint_as_float(((unsigned int)h) << 16);
}
static __device__ __forceinline__ sh8 lds8(const unsigned short* p){ return *reinterpret_cast<const sh8*>(p); }

// async global->LDS, 16B per lane; LDS dest is wave-uniform base + lane*16
static __device__ __forceinline__ void stage16(const unsigned short* g, unsigned short* l){
    __builtin_amdgcn_global_load_lds(
        (const __attribute__((address_space(1))) unsigned int*)g,
        (__attribute__((address_space(3))) unsigned int*)l, 16, 0, 0);
}

// ---------------- CSR build ----------------
__global__ __launch_bounds__(256) void k_count(const int* dst, int* deg){
    int i = blockIdx.x*256 + threadIdx.x;
    if (i < EE) atomicAdd(&deg[dst[i]], 1);
}

__global__ __launch_bounds__(256) void k_dinv(const int* deg, float* dinv){
    int n = blockIdx.x*256 + threadIdx.x;
    if (n < NN) dinv[n] = rsqrtf((float)deg[n] + 1.0f);
}

__global__ __launch_bounds__(1024) void k_scan(const int* cnt, int* rows){
    __shared__ int part[1024];
    int t = threadIdx.x;
    int base = t*20;
    int s = 0;
    for (int i = 0; i < 20; ++i){ int idx = base+i; if (idx < NN) s += cnt[idx]; }
    part[t] = s; __syncthreads();
    for (int off = 1; off < 1024; off <<= 1){
        int v = (t >= off) ? part[t-off] : 0;
        __syncthreads();
        part[t] += v;
        __syncthreads();
    }
    int run = part[t] - s;   // exclusive
    for (int i = 0; i < 20; ++i){
        int idx = base+i;
        if (idx < NN){ rows[idx] = run; run += cnt[idx]; }
    }
    if (t == 0) rows[NN] = EE;
}

__global__ __launch_bounds__(256) void k_fill(const int* src, const int* dst, const int* rows,
                                              int* cursor, int* col){
    int i = blockIdx.x*256 + threadIdx.x;
    if (i < EE){
        int d = dst[i];
        int pos = rows[d] + atomicAdd(&cursor[d], 1);
        col[pos] = src[i];
    }
}

// ---------------- weight transpose+convert ----------------
__global__ __launch_bounds__(256) void conv_wT(cfp w0, cfp w1, cfp w2, cfp w3, cfp w4, cfp w5, cfp w6,
                                               unsigned short* wts){
    const float* in;
    switch (blockIdx.z){
        case 0: in = w0; break; case 1: in = w1; break; case 2: in = w2; break;
        case 3: in = w3; break; case 4: in = w4; break; case 5: in = w5; break;
        default: in = w6; break;
    }
    unsigned short* out = wts + (size_t)blockIdx.z*16384;
    __shared__ float t[64][65];
    int r0 = blockIdx.x*64, c0 = blockIdx.y*64;
    int tid = threadIdx.x;
    for (int i = tid; i < 64*16; i += 256){
        int r = i >> 4, c4 = (i & 15) * 4;
        float4 v = ld4(in + (size_t)(r0+r)*128 + c0 + c4);
        t[r][c4+0]=v.x; t[r][c4+1]=v.y; t[r][c4+2]=v.z; t[r][c4+3]=v.w;
    }
    __syncthreads();
    for (int i = tid; i < 64*16; i += 256){
        int c = i >> 4, r4 = (i & 15) * 4;
        ushort4 o;
        o.x = f2bf(t[r4+0][c]); o.y = f2bf(t[r4+1][c]);
        o.z = f2bf(t[r4+2][c]); o.w = f2bf(t[r4+3][c]);
        *reinterpret_cast<ushort4*>(out + (size_t)(c0+c)*128 + r0 + r4) = o;
    }
}

// ---------------- fp32 GEMM (KK-sized only) ----------------
__global__ __launch_bounds__(512) void gemm128(const float* __restrict__ A, const float* __restrict__ Wm,
                                               float* __restrict__ C, int M,
                                               const float* bias, const float* resid, int relu){
    __shared__ __align__(16) float Ws[128*132];
    __shared__ float As[64*129];
    int tid = threadIdx.x;
    int r0 = blockIdx.x*64;
    for (int i = tid; i < 128*32; i += 512){
        int r = i >> 5, c4 = (i & 31) * 4;
        float4 v = ld4(Wm + r*128 + c4);
        st4(&Ws[r*132 + c4], v);
    }
    for (int i = tid; i < 64*32; i += 512){
        int r = i >> 5, c4 = (i & 31) * 4;
        float4 v = (r0 + r < M) ? ld4(A + (size_t)(r0+r)*128 + c4) : make_float4(0,0,0,0);
        As[r*129 + c4+0] = v.x; As[r*129 + c4+1] = v.y;
        As[r*129 + c4+2] = v.z; As[r*129 + c4+3] = v.w;
    }
    __syncthreads();
    int a = tid >> 5;
    int b = tid & 31;
    float acc[4][4] = {};
    #pragma unroll 4
    for (int d = 0; d < 128; ++d){
        float4 w = ld4(&Ws[d*132 + 4*b]);
        float wv[4] = {w.x, w.y, w.z, w.w};
        float av[4];
        #pragma unroll
        for (int i = 0; i < 4; ++i) av[i] = As[(4*a+i)*129 + d];
        #pragma unroll
        for (int i = 0; i < 4; ++i)
            #pragma unroll
            for (int j = 0; j < 4; ++j)
                acc[i][j] += av[i]*wv[j];
    }
    int cc = 4*b;
    #pragma unroll
    for (int i = 0; i < 4; ++i){
        int r = r0 + 4*a + i;
        if (r < M){
            float v[4];
            #pragma unroll
            for (int j = 0; j < 4; ++j) v[j] = acc[i][j];
            if (bias){
                #pragma unroll
                for (int j = 0; j < 4; ++j) v[j] += bias[cc+j];
            }
            if (relu){
                #pragma unroll
                for (int j = 0; j < 4; ++j) v[j] = fmaxf(v[j], 0.f);
            }
            if (resid){
                float4 rv = ld4(resid + (size_t)r*128 + cc);
                v[0]+=rv.x; v[1]+=rv.y; v[2]+=rv.z; v[3]+=rv.w;
            }
            st4(C + (size_t)r*128 + cc, make_float4(v[0],v[1],v[2],v[3]));
        }
    }
}

// ---------------- bf16 MFMA GEMM: C[M x 128] = (A@W)*rscale, bf16 out ----------------
__global__ __launch_bounds__(256) void tgemm(const unsigned short* __restrict__ A, int M,
                                             const unsigned short* __restrict__ Wt,
                                             const float* __restrict__ rscale,
                                             unsigned short* __restrict__ C){
    int tid = threadIdx.x;
    int wave = tid >> 6, lane = tid & 63;
    int wm = wave >> 1, wn = wave & 1;
    int m_base = blockIdx.x*64 + wm*32;
    int n_base = blockIdx.y*64 + wn*32;
    int l15 = lane & 15;
    int roff = (lane >> 4) * 8;
    const unsigned short* ap0 = A + (size_t)(m_base + l15)*128 + roff;
    const unsigned short* ap1 = ap0 + 16*128;
    const unsigned short* b0p = Wt + (size_t)(n_base + l15)*128 + roff;
    const unsigned short* b1p = b0p + 16*128;
    f32x4 acc00 = (f32x4)0.f, acc01 = (f32x4)0.f, acc10 = (f32x4)0.f, acc11 = (f32x4)0.f;
    #pragma unroll
    for (int r = 0; r < 128; r += 32){
        sh8 a0 = lds8(ap0 + r);
        sh8 a1 = lds8(ap1 + r);
        sh8 b0 = lds8(b0p + r);
        sh8 b1 = lds8(b1p + r);
        acc00 = __builtin_amdgcn_mfma_f32_16x16x32_bf16(a0, b0, acc00, 0, 0, 0);
        acc01 = __builtin_amdgcn_mfma_f32_16x16x32_bf16(a0, b1, acc01, 0, 0, 0);
        acc10 = __builtin_amdgcn_mfma_f32_16x16x32_bf16(a1, b0, acc10, 0, 0, 0);
        acc11 = __builtin_amdgcn_mfma_f32_16x16x32_bf16(a1, b1, acc11, 0, 0, 0);
    }
    int rq = (lane >> 4) * 4;
    f32x4 accs[2][2] = {{acc00, acc01},{acc10, acc11}};
    #pragma unroll
    for (int mi = 0; mi < 2; ++mi){
        #pragma unroll
        for (int ni = 0; ni < 2; ++ni){
            f32x4 a = accs[mi][ni];
            int gn = n_base + ni*16 + l15;
            #pragma unroll
            for (int reg = 0; reg < 4; ++reg){
                int gm = m_base + mi*16 + rq + reg;
                if (gm < M) C[(size_t)gm*128 + gn] = f2bf(a[reg] * (rscale ? rscale[gm] : 1.f));
            }
        }
    }
}

// ---------------- GCN aggregation (bf16 in, fp32 accumulate), neighbor unroll 8 ----------------
__global__ __launch_bounds__(256) void gcn_agg_bf(const unsigned short* __restrict__ y, const float* __restrict__ dinv,
                                                  const int* __restrict__ rows, const int* __restrict__ col,
                                                  const float* __restrict__ bias, void* __restrict__ outv,
                                                  int relu, int out_fp32){
    int wid = (int)((blockIdx.x*256 + threadIdx.x) >> 6);
    int lane = threadIdx.x & 63;
    if (wid >= NN) return;
    int f = lane*2;
    ushort2 u = *reinterpret_cast<const ushort2*>(y + (size_t)wid*128 + f);
    float ax = bf2f(u.x), ay = bf2f(u.y);
    int s = rows[wid], e = rows[wid+1];
    int j = s;
    int e8 = s + ((e - s) & ~7);
    for (; j < e8; j += 8){
        ushort2 v[8];
        #pragma unroll
        for (int q = 0; q < 8; ++q){
            int c = col[j+q];
            v[q] = *reinterpret_cast<const ushort2*>(y + (size_t)c*128 + f);
        }
        #pragma unroll
        for (int q = 0; q < 8; ++q){ ax += bf2f(v[q].x); ay += bf2f(v[q].y); }
    }
    for (; j < e; ++j){
        int c0 = col[j];
        ushort2 v0 = *reinterpret_cast<const ushort2*>(y + (size_t)c0*128 + f);
        ax += bf2f(v0.x); ay += bf2f(v0.y);
    }
    float dn = dinv[wid];
    float ox = ax*dn + bias[f];
    float oy = ay*dn + bias[f+1];
    if (relu){ ox = fmaxf(ox, 0.f); oy = fmaxf(oy, 0.f); }
    if (out_fp32){
        *reinterpret_cast<float2*>((float*)outv + (size_t)wid*128 + f) = make_float2(ox, oy);
    } else {
        ushort2 o; o.x = f2bf(ox); o.y = f2bf(oy);
        *reinterpret_cast<ushort2*>((unsigned short*)outv + (size_t)wid*128 + f) = o;
    }
}

// ---------------- fused K/V aggregation: one CSR walk, two gathers ----------------
// K: bf16 out (bias bk, no relu); V: fp32 out (bias bv, no relu).
__global__ __launch_bounds__(256) void gcn_agg_kv(const unsigned short* __restrict__ yk,
                                                  const unsigned short* __restrict__ yv,
                                                  const float* __restrict__ dinv,
                                                  const int* __restrict__ rows, const int* __restrict__ col,
                                                  const float* __restrict__ bk, const float* __restrict__ bv,
                                                  unsigned short* __restrict__ outk, float* __restrict__ outv){
    int wid = (int)((blockIdx.x*256 + threadIdx.x) >> 6);
    int lane = threadIdx.x & 63;
    if (wid >= NN) return;
    int f = lane*2;
    ushort2 uk = *reinterpret_cast<const ushort2*>(yk + (size_t)wid*128 + f);
    ushort2 uv = *reinterpret_cast<const ushort2*>(yv + (size_t)wid*128 + f);
    float kx = bf2f(uk.x), ky = bf2f(uk.y);
    float vx = bf2f(uv.x), vy = bf2f(uv.y);
    int s = rows[wid], e = rows[wid+1];
    int j = s;
    int e8 = s + ((e - s) & ~7);
    for (; j < e8; j += 8){
        ushort2 a[8], b[8];
        #pragma unroll
        for (int q = 0; q < 8; ++q){
            int c = col[j+q];
            a[q] = *reinterpret_cast<const ushort2*>(yk + (size_t)c*128 + f);
            b[q] = *reinterpret_cast<const ushort2*>(yv + (size_t)c*128 + f);
        }
        #pragma unroll
        for (int q = 0; q < 8; ++q){
            kx += bf2f(a[q].x); ky += bf2f(a[q].y);
            vx += bf2f(b[q].x); vy += bf2f(b[q].y);
        }
    }
    for (; j < e; ++j){
        int c0 = col[j];
        ushort2 a0 = *reinterpret_cast<const ushort2*>(yk + (size_t)c0*128 + f);
        ushort2 b0 = *reinterpret_cast<const ushort2*>(yv + (size_t)c0*128 + f);
        kx += bf2f(a0.x); ky += bf2f(a0.y);
        vx += bf2f(b0.x); vy += bf2f(b0.y);
    }
    float dn = dinv[wid];
    ushort2 ok;
    ok.x = f2bf(kx*dn + bk[f]);
    ok.y = f2bf(ky*dn + bk[f+1]);
    *reinterpret_cast<ushort2*>(outk + (size_t)wid*128 + f) = ok;
    *reinterpret_cast<float2*>(outv + (size_t)wid*128 + f) = make_float2(vx*dn + bv[f], vy*dn + bv[f+1]);
}

// ---------------- convert fp32 -> bf16 ----------------
__global__ __launch_bounds__(256) void conv_bf16(const float* __restrict__ in, unsigned short* __restrict__ out, int n4){
    int i = blockIdx.x*256 + threadIdx.x;
    if (i < n4){
        float4 v = ld4(in + (size_t)i*4);
        ushort4 o;
        o.x = f2bf(v.x); o.y = f2bf(v.y); o.z = f2bf(v.z); o.w = f2bf(v.w);
        *reinterpret_cast<ushort4*>(out + (size_t)i*4) = o;
    }
}

// ---------------- convert + transpose (+ optional per-source-row scale) ----------------
__global__ __launch_bounds__(256) void conv_bf16_T(const float* __restrict__ in, unsigned short* __restrict__ out,
                                                   int M, int ldout, const float* __restrict__ rscale){
    __shared__ float t[64][65];
    int r0 = blockIdx.x*64, c0 = blockIdx.y*64;
    int tid = threadIdx.x;
    for (int i = tid; i < 64*16; i += 256){
        int r = i >> 4, c4 = (i & 15) * 4;
        float4 v = (r0 + r < M) ? ld4(in + (size_t)(r0+r)*128 + c0 + c4) : make_float4(0,0,0,0);
        if (rscale && r0 + r < M){
            float sc = rscale[r0 + r];
            v.x *= sc; v.y *= sc; v.z *= sc; v.w *= sc;
        }
        t[r][c4+0]=v.x; t[r][c4+1]=v.y; t[r][c4+2]=v.z; t[r][c4+3]=v.w;
    }
    __syncthreads();
    for (int i = tid; i < 64*16; i += 256){
        int c = i >> 4, r4 = (i & 15) * 4;
        if (r0 + r4 < M){
            ushort4 o;
            o.x = f2bf(t[r4+0][c]); o.y = f2bf(t[r4+1][c]);
            o.z = f2bf(t[r4+2][c]); o.w = f2bf(t[r4+3][c]);
            *reinterpret_cast<ushort4*>(out + (size_t)(c0+c)*ldout + r0 + r4) = o;
        }
    }
}

// ---------------- z reduction: zinv[n] = 1/sum, zdinv[n] = zinv[n]*dinv[n] ----------------
__global__ __launch_bounds__(256) void k_rcp32(const float* __restrict__ zp, const float* __restrict__ dinv,
                                               float* __restrict__ zinv, float* __restrict__ zdinv){
    int n = blockIdx.x*256 + threadIdx.x;
    if (n < NN){
        float s = 0.f;
        #pragma unroll
        for (int y = 0; y < ZCH; ++y) s += zp[(size_t)y*NN + n];
        float zi = 1.f / s;
        zinv[n] = zi;
        zdinv[n] = zi * dinv[n];
    }
}

// ---------------- S-GEMM + exp + z-partials ----------------
// grid (313 n-blocks, ZCH k-chunks). Wave-private quadrant staging: each wave owns a
// 32x32 quadrant end-to-end (MFMA -> exp -> private LDS -> global), NO barriers in the
// k-loop (per-wave in-order DS pipe orders the LDS write->read). Waves slip freely.
__global__ __launch_bounds__(256) void s_gemm_exp(const unsigned short* __restrict__ Kb,
                                                  const unsigned short* __restrict__ Qb2,
                                                  unsigned short* __restrict__ E, float* __restrict__ zpart){
    __shared__ unsigned short Es[4][32*36];   // per-wave private quadrant, pad 36
    __shared__ float zsh[2][64];
    int tid = threadIdx.x;
    int wave = tid >> 6, lane = tid & 63;
    int wm = wave >> 1, wn = wave & 1;
    int n_blk = blockIdx.x*64;
    int k_base = blockIdx.y*512;
    int l15 = lane & 15;
    int h = lane >> 4;
    int roff = h * 8;
    int rq = h * 4;
    unsigned short* myEs = Es[wave];
    // Kd fragments (reused across all 8 k-blocks)
    const unsigned short* ap0 = Kb + (size_t)(n_blk + wm*32 + l15)*128 + roff;
    const unsigned short* ap1 = ap0 + 16*128;
    sh8 a0[4], a1[4];
    #pragma unroll
    for (int r = 0; r < 4; ++r){ a0[r] = lds8(ap0 + r*32); a1[r] = lds8(ap1 + r*32); }
    // Q fragments, double buffered
    const unsigned short* qbase = Qb2 + (size_t)(k_base + wn*32 + l15)*128 + roff;
    sh8 q0[4], q1[4];
    #pragma unroll
    for (int r = 0; r < 4; ++r){ q0[r] = lds8(qbase + r*32); q1[r] = lds8(qbase + 16*128 + r*32); }
    float zacc[2][4] = {{0.f,0.f,0.f,0.f},{0.f,0.f,0.f,0.f}};
    for (int kb = 0; kb < 8; ++kb){
        sh8 n0[4], n1[4];
        if (kb < 7){
            const unsigned short* qn = qbase + (size_t)(kb+1)*64*128;
            #pragma unroll
            for (int r = 0; r < 4; ++r){ n0[r] = lds8(qn + r*32); n1[r] = lds8(qn + 16*128 + r*32); }
        } else {
            #pragma unroll
            for (int r = 0; r < 4; ++r){ n0[r] = (sh8)0; n1[r] = (sh8)0; }
        }
        f32x4 acc00 = (f32x4)0.f, acc01 = (f32x4)0.f, acc10 = (f32x4)0.f, acc11 = (f32x4)0.f;
        #pragma unroll
        for (int r = 0; r < 4; ++r){
            acc00 = __builtin_amdgcn_mfma_f32_16x16x32_bf16(a0[r], q0[r], acc00, 0, 0, 0);
            acc01 = __builtin_amdgcn_mfma_f32_16x16x32_bf16(a0[r], q1[r], acc01, 0, 0, 0);
            acc10 = __builtin_amdgcn_mfma_f32_16x16x32_bf16(a1[r], q0[r], acc10, 0, 0, 0);
            acc11 = __builtin_amdgcn_mfma_f32_16x16x32_bf16(a1[r], q1[r], acc11, 0, 0, 0);
        }
        int kcol = k_base + kb*64;
        f32x4 accs[2][2] = {{acc00, acc01},{acc10, acc11}};
        // exp + write own quadrant to private LDS (rows 0..31 = quadrant rows, cols 0..31)
        #pragma unroll
        for (int mi = 0; mi < 2; ++mi){
            #pragma unroll
            for (int ni = 0; ni < 2; ++ni){
                f32x4 a = accs[mi][ni];
                bool kv = (kcol + wn*32 + ni*16 + l15) < KK;
                #pragma unroll
                for (int reg = 0; reg < 4; ++reg){
                    float e = kv ? __expf(a[reg]*SCALE) : 0.f;
                    myEs[(mi*16 + rq + reg)*36 + ni*16 + l15] = f2bf(e);
                    zacc[mi][reg] += e;
                }
            }
        }
        // read back own quadrant (b128) and store to global (64B row segments)
        #pragma unroll
        for (int it = 0; it < 2; ++it){
            int r = it*16 + (lane >> 2);
            int q4 = (lane & 3) * 8;
            sh8 v = lds8(myEs + r*36 + q4);
            int gr = n_blk + wm*32 + r;
            if (gr < NN)
                *reinterpret_cast<sh8*>(E + (size_t)gr*KP + kcol + wn*32 + q4) = v;
        }
        #pragma unroll
        for (int r = 0; r < 4; ++r){ q0[r] = n0[r]; q1[r] = n1[r]; }
    }
    // z reduction: sum over the 16 lanes of each l15-group (covers this wave's 32 cols)
    #pragma unroll
    for (int mi = 0; mi < 2; ++mi){
        #pragma unroll
        for (int reg = 0; reg < 4; ++reg){
            float v = zacc[mi][reg];
            v += __shfl_xor(v, 1);
            v += __shfl_xor(v, 2);
            v += __shfl_xor(v, 4);
            v += __shfl_xor(v, 8);
            zacc[mi][reg] = v;
        }
    }
    if (l15 == 0){
        #pragma unroll
        for (int mi = 0; mi < 2; ++mi)
            #pragma unroll
            for (int reg = 0; reg < 4; ++reg)
                zsh[wn][wm*32 + mi*16 + h*4 + reg] = zacc[mi][reg];
    }
    __syncthreads();
    if (tid < 64){
        int n = n_blk + tid;
        if (n < NN) zpart[(size_t)blockIdx.y*NN + n] = zsh[0][tid] + zsh[1][tid];
    }
}

// ---------------- attn GEMM partials with next-chunk prefetch ----------------
__global__ __launch_bounds__(256) void attn_gemm(const unsigned short* __restrict__ E,
                                                 const unsigned short* __restrict__ Vt,
                                                 float* __restrict__ part){
    __shared__ unsigned short As[64*36];
    int tid = threadIdx.x;
    int wave = tid >> 6, lane = tid & 63;
    int kk0 = blockIdx.x*64;
    int per = (ACHUNKS + ZSPLIT - 1) / ZSPLIT;
    int c0 = blockIdx.y*per;
    int c1 = min(ACHUNKS, c0 + per);
    int l15 = lane & 15;
    int q8 = (lane >> 4) * 8;
    int d0 = wave*32;
    int n_l = tid & 31;
    int k8 = (tid >> 5) * 8;
    f32x4 acc[4][2];
    #pragma unroll
    for (int g = 0; g < 4; ++g){ acc[g][0] = (f32x4)0.f; acc[g][1] = (f32x4)0.f; }
    const unsigned short* ebase = E + (size_t)n_l*KP + kk0 + k8;
    const unsigned short* vb0p = Vt + (size_t)(d0 + l15)*NN + q8;
    const unsigned short* vb1p = vb0p + (size_t)16*NN;
    sh8 etmp = lds8(ebase + (size_t)c0*32*KP);
    sh8 vb0 = lds8(vb0p + c0*32);
    sh8 vb1 = lds8(vb1p + c0*32);
    for (int ch = c0; ch < c1; ++ch){
        unsigned short tmp[8];
        *reinterpret_cast<sh8*>(tmp) = etmp;
        #pragma unroll
        for (int j = 0; j < 8; ++j) As[(k8 + j)*36 + n_l] = tmp[j];
        __syncthreads();
        sh8 etn = (sh8)0, vbn0 = (sh8)0, vbn1 = (sh8)0;
        if (ch + 1 < c1){
            etn  = lds8(ebase + (size_t)(ch+1)*32*KP);
            vbn0 = lds8(vb0p + (ch+1)*32);
            vbn1 = lds8(vb1p + (ch+1)*32);
        }
        #pragma unroll
        for (int g = 0; g < 4; ++g){
            const unsigned short* ap = &As[(g*16 + l15)*36 + q8];
            union { struct { ushort4 lo, hi; } u; sh8 v; } af;
            af.u.lo = *reinterpret_cast<const ushort4*>(ap);
            af.u.hi = *reinterpret_cast<const ushort4*>(ap + 4);
            acc[g][0] = __builtin_amdgcn_mfma_f32_16x16x32_bf16(af.v, vb0, acc[g][0], 0, 0, 0);
            acc[g][1] = __builtin_amdgcn_mfma_f32_16x16x32_bf16(af.v, vb1, acc[g][1], 0, 0, 0);
        }
        __syncthreads();
        etmp = etn; vb0 = vbn0; vb1 = vbn1;
    }
    float* pbase = part + (size_t)blockIdx.y*KK*128;
    int rq = (lane >> 4) * 4;
    #pragma unroll
    for (int g = 0; g < 4; ++g){
        #pragma unroll
        for (int ni = 0; ni < 2; ++ni){
            int d = d0 + ni*16 + l15;
            #pragma unroll
            for (int reg = 0; reg < 4; ++reg){
                int kk = kk0 + g*16 + rq + reg;
                if (kk < KK) pbase[(size_t)kk*128 + d] = acc[g][ni][reg];
            }
        }
    }
}

// ---------------- xout GEMM: full K=2048 sweep, LDS-staged E (swizzled), bf16 out fused with zdinv ----------------
// grid 625 blocks x 256 threads. Block: E rows [m_base, m_base+32), all 128 d-cols.
// E tile (32 rows x 128 k = 8KB) staged via global_load_lds, double-buffered.
// LDS layout: linear [row][kb], swizzle: LDS[row][kb] = E[row][kb ^ ((row&15)<<4)]
// (swizzle pre-applied to the GLOBAL source addr; read applies same XOR to the FULL in-row byte offset).
__global__ __launch_bounds__(256) void xout_gemm(const unsigned short* __restrict__ E,
                                                 const unsigned short* __restrict__ B,
                                                 const float* __restrict__ zdinv,
                                                 unsigned short* __restrict__ out){
    __shared__ __align__(16) unsigned short ebuf[2][4096];   // 2 x 8 KB
    int tid = threadIdx.x;
    int wave = tid >> 6, lane = tid & 63;
    int l15 = lane & 15;
    int h = lane >> 4;
    int m_base = blockIdx.x*32;
    int srow0 = wave*4 + h;            // issue 0 row (0..15)
    int skb0  = (l15*16) ^ ((srow0 & 15) << 4);
    int srow1 = 16 + srow0;            // issue 1 row (16..31)
    int skb1  = (l15*16) ^ ((srow1 & 15) << 4);
    const unsigned short* g0 = E + (size_t)(m_base + srow0)*KP + (skb0 >> 1);
    const unsigned short* g1 = E + (size_t)(m_base + srow1)*KP + (skb1 >> 1);
    unsigned short* l0 = &ebuf[0][wave*512];          // + issue*2048 ushorts
    unsigned short* l1 = &ebuf[1][wave*512];
    const unsigned short* bp0 = B + (size_t)(wave*32 + l15)*KP + h*8;
    const unsigned short* bp1 = bp0 + (size_t)16*KP;
    int rswz = l15 << 4;

    f32x4 acc[2][2];
    #pragma unroll
    for (int mi = 0; mi < 2; ++mi)
        #pragma unroll
        for (int ni = 0; ni < 2; ++ni) acc[mi][ni] = (f32x4)0.f;

    // prologue: stage tile 0, load B tile 0
    stage16(g0, l0);
    stage16(g1, l0 + 2048);
    sh8 b0[4], b1[4];
    #pragma unroll
    for (int s = 0; s < 4; ++s){ b0[s] = lds8(bp0 + s*32); b1[s] = lds8(bp1 + s*32); }
    __syncthreads();

    for (int t = 0; t < 16; ++t){
        if (t < 15){
            const unsigned short* ng0 = g0 + (t+1)*128;
            const unsigned short* ng1 = g1 + (t+1)*128;
            unsigned short* nl = (t & 1) ? l0 : l1;
            stage16(ng0, nl);
            stage16(ng1, nl + 2048);
        }
        sh8 nb0[4], nb1[4];
        if (t < 15){
            #pragma unroll
            for (int s = 0; s < 4; ++s){
                nb0[s] = lds8(bp0 + (t+1)*128 + s*32);
                nb1[s] = lds8(bp1 + (t+1)*128 + s*32);
            }
        } else {
            #pragma unroll
            for (int s = 0; s < 4; ++s){ nb0[s] = (sh8)0; nb1[s] = (sh8)0; }
        }
        const unsigned short* eb = (t & 1) ? ebuf[1] : ebuf[0];
        #pragma unroll
        for (int s = 0; s < 4; ++s){
            int ko = ((h*16 + s*64) ^ rswz) >> 1;     // ushort offset within row, stays < 128
            sh8 a0 = lds8(eb + l15*128 + ko);
            sh8 a1 = lds8(eb + (16 + l15)*128 + ko);
            acc[0][0] = __builtin_amdgcn_mfma_f32_16x16x32_bf16(a0, b0[s], acc[0][0], 0, 0, 0);
            acc[0][1] = __builtin_amdgcn_mfma_f32_16x16x32_bf16(a0, b1[s], acc[0][1], 0, 0, 0);
            acc[1][0] = __builtin_amdgcn_mfma_f32_16x16x32_bf16(a1, b0[s], acc[1][0], 0, 0, 0);
            acc[1][1] = __builtin_amdgcn_mfma_f32_16x16x32_bf16(a1, b1[s], acc[1][1], 0, 0, 0);
        }
        __syncthreads();
        #pragma unroll
        for (int s = 0; s < 4; ++s){ b0[s] = nb0[s]; b1[s] = nb1[s]; }
    }

    int rq = h*4;
    #pragma unroll
    for (int mi = 0; mi < 2; ++mi){
        #pragma unroll
        for (int ni = 0; ni < 2; ++ni){
            f32x4 a = acc[mi][ni];
            int d = wave*32 + ni*16 + l15;
            #pragma unroll
            for (int reg = 0; reg < 4; ++reg){
                int gm = m_base + mi*16 + rq + reg;
                out[(size_t)gm*128 + d] = f2bf(a[reg] * zdinv[gm]);
            }
        }
    }
}

// ---------------- LayerNorm over D=128 (with partial-sum input) ----------------
__global__ __launch_bounds__(128) void ln_ker(const float* __restrict__ in, int nparts,
                                              const float* __restrict__ resid,
                                              const float* __restrict__ g, const float* __restrict__ be,
                                              float* __restrict__ out){
    __shared__ float rs[128], rq[128];
    int r = blockIdx.x, t = threadIdx.x;
    float v = 0.f;
    for (int p = 0; p < nparts; ++p) v += in[(size_t)p*KK*128 + r*128 + t];
    if (resid) v += resid[r*128 + t];
    rs[t] = v; rq[t] = v*v;
    __syncthreads();
    for (int off = 64; off > 0; off >>= 1){
        if (t < off){ rs[t] += rs[t+off]; rq[t] += rq[t+off]; }
        __syncthreads();
    }
    float mean = rs[0]*(1.f/128.f);
    float var = rq[0]*(1.f/128.f) - mean*mean;
    out[r*128 + t] = (v - mean)*rsqrtf(var + 1e-5f)*g[t] + be[t];
}

// ---------------- launcher ----------------
extern "C" void kernel_launch(void* const* d_in, const int* in_sizes, int n_in,
                              void* d_out, int out_size, void* d_ws, size_t ws_size,
                              hipStream_t stream){
    cfp x  = (cfp)d_in[0];
    const int* ei = (const int*)d_in[1];
    const int* esrc = ei;
    const int* edst = ei + EE;
    cfp W1=(cfp)d_in[3], b1=(cfp)d_in[4], W2=(cfp)d_in[5], b2=(cfp)d_in[6];
    cfp S =(cfp)d_in[7];
    cfp Wq=(cfp)d_in[8],  bq=(cfp)d_in[9],  Wk=(cfp)d_in[10], bk=(cfp)d_in[11];
    cfp Wv=(cfp)d_in[12], bv=(cfp)d_in[13], Wo=(cfp)d_in[14], bo=(cfp)d_in[15];
    cfp g0=(cfp)d_in[16], be0=(cfp)d_in[17], g1=(cfp)d_in[18], be1=(cfp)d_in[19];
    cfp Wl=(cfp)d_in[20], bl=(cfp)d_in[21], W3=(cfp)d_in[22], b3=(cfp)d_in[23];
    cfp W4=(cfp)d_in[24], b4=(cfp)d_in[25], W5=(cfp)d_in[26], b5=(cfp)d_in[27];

    char* wsb = (char*)d_ws;
    const size_t MB = 1048576;
    int*   deg    = (int*)  (wsb + 0);
    float* dinv   = (float*)(wsb + 81920);
    int*   rows   = (int*)  (wsb + 163840);
    int*   cursor = (int*)  (wsb + 245760);
    int*   col    = (int*)  (wsb + 327680);
    float* Qb     = (float*)(wsb + 2*MB);
    float* o1     = (float*)(wsb + 3*MB);    // also xl3 (fp32)
    float* o2     = (float*)(wsb + 4*MB);
    float* o3     = (float*)(wsb + 5*MB);
    float* xlb    = (float*)(wsb + 6*MB);
    float* zpart  = (float*)(wsb + 7*MB);                 // ZCH x NN fp32
    float* zinv   = (float*)(wsb + 10*MB);
    float* zdinv  = (float*)(wsb + 10*MB + 131072);
    unsigned short* Wts  = (unsigned short*)(wsb + 10*MB + 262144);
    unsigned short* Qbf  = (unsigned short*)(wsb + 11*MB);
    unsigned short* xlt3 = (unsigned short*)(wsb + 11*MB + 524288);  // [128 x KP] bf16
    unsigned short* xbf = (unsigned short*)(wsb + 12*MB); // also h3
    unsigned short* h1  = (unsigned short*)(wsb + 17*MB); // also h4
    unsigned short* h2  = (unsigned short*)(wsb + 22*MB);
    unsigned short* ybuf= (unsigned short*)(wsb + 27*MB);
    unsigned short* Kbf = (unsigned short*)(wsb + 32*MB);
    unsigned short* Vtz = (unsigned short*)(wsb + 37*MB);
    // time-aliased region 42..62 MiB: NB3 (Vd fp32, 42..51.8) + ybufV (52..57, dead before part) -> part (16 MiB from 42)
    float* NB3    = (float*)(wsb + 42*MB);
    unsigned short* ybufV = (unsigned short*)(wsb + 52*MB);
    float* part   = (float*)(wsb + 42*MB);
    unsigned short* E = (unsigned short*)(wsb + 62*MB);   // [NN x KP] bf16 = 78.1 MiB -> ends ~140.1 MiB
    float* outp   = (float*)d_out;
    unsigned short* h3 = xbf;
    unsigned short* h4 = h1;

    (void)hipMemsetAsync(deg, 0, NN*sizeof(int), stream);
    (void)hipMemsetAsync(cursor, 0, NN*sizeof(int), stream);
    (void)hipMemsetAsync(xlt3, 0, 128*KP*sizeof(unsigned short), stream);  // pad cols must be finite

    // CSR build
    k_count<<<1250, 256, 0, stream>>>(edst, deg);
    k_dinv<<<79, 256, 0, stream>>>(deg, dinv);
    k_scan<<<1, 1024, 0, stream>>>(deg, rows);
    k_fill<<<1250, 256, 0, stream>>>(esrc, edst, rows, cursor, col);

    // weights -> bf16 transposed; x -> bf16
    conv_wT<<<dim3(2,2,7), 256, 0, stream>>>(W1, W2, Wk, Wv, W3, W4, W5, Wts);
    conv_bf16<<<2500, 256, 0, stream>>>(x, xbf, NN*32);
    unsigned short* W1t = Wts;
    unsigned short* W2t = Wts + 16384;
    unsigned short* Wkt = Wts + 2*16384;
    unsigned short* Wvt = Wts + 3*16384;
    unsigned short* W4t = Wts + 5*16384;
    unsigned short* W5t = Wts + 6*16384;

    const int GN = 313;   // ceil(NN/64)
    const int GK = 32;    // ceil(KK/64) == KP/64

    // GCN1
    tgemm<<<dim3(GN,2), 256, 0, stream>>>(xbf, NN, W1t, dinv, ybuf);
    gcn_agg_bf<<<5000, 256, 0, stream>>>(ybuf, dinv, rows, col, b1, h1, 1, 0);
    // GCN2 -> h2
    tgemm<<<dim3(GN,2), 256, 0, stream>>>(h1, NN, W2t, dinv, ybuf);
    gcn_agg_bf<<<5000, 256, 0, stream>>>(ybuf, dinv, rows, col, b2, h2, 1, 0);
    // K and V pre-agg GEMMs (both from h2), then ONE fused gather pass
    tgemm<<<dim3(GN,2), 256, 0, stream>>>(h2, NN, Wkt, dinv, ybuf);
    tgemm<<<dim3(GN,2), 256, 0, stream>>>(h2, NN, Wvt, dinv, ybufV);
    gcn_agg_kv<<<5000, 256, 0, stream>>>(ybuf, ybufV, dinv, rows, col, bk, bv, Kbf, NB3);
    // Q = S@Wq + bq (fp32) -> Qbf
    gemm128<<<GK, 512, 0, stream>>>(S, Wq, Qb, KK, bq, nullptr, 0);
    conv_bf16<<<250, 256, 0, stream>>>(Qb, Qbf, KK*32);
    // E = exp(SCALE * Kd Q^T), z partials (reg-cached Kd, 4 k-chunks, wave-private staging)
    s_gemm_exp<<<dim3(GN, ZCH), 256, 0, stream>>>(Kbf, Qbf, E, zpart);
    k_rcp32<<<79, 256, 0, stream>>>(zpart, dinv, zinv, zdinv);
    // Vd (NB3, fp32) -> Vtz (transposed bf16, pre-scaled by zinv[n])
    conv_bf16_T<<<dim3(GN, 2), 256, 0, stream>>>(NB3, Vtz, NN, NN, zinv);
    // attn partials (NB3/ybufV dead now; part aliases the region)
    attn_gemm<<<dim3(GK, ZSPLIT), 256, 0, stream>>>(E, Vtz, part);
    // out = LN(sum(part) + Q)
    ln_ker<<<KK, 128, 0, stream>>>(part, ZSPLIT, Qb, g0, be0, o1);
    // o2 = o1 + relu(o1@Wo + bo)
    gemm128<<<GK, 512, 0, stream>>>(o1, Wo, o2, KK, bo, o1, 1);
    ln_ker<<<KK, 128, 0, stream>>>(o2, 1, nullptr, g1, be1, o3);
    // xl = o3@Wl + bl ; xl3 = xl @ W3  (GCN3 weight folded into the seed side)
    gemm128<<<GK, 512, 0, stream>>>(o3, Wl, xlb, KK, bl, nullptr, 0);
    gemm128<<<GK, 512, 0, stream>>>(xlb, W3, o1, KK, nullptr, nullptr, 0);
    conv_bf16_T<<<dim3(GK, 2), 256, 0, stream>>>(o1, xlt3, KK, KP, nullptr);
    // ybuf[n] = bf16(zinv*dinv*(E[n] @ xl3)) == GCN3 pre-agg activations (fused, no partials)
    xout_gemm<<<625, 256, 0, stream>>>(E, xlt3, zdinv, ybuf);
    // GCN3 aggregation
    gcn_agg_bf<<<5000, 256, 0, stream>>>(ybuf, dinv, rows, col, b3, h3, 1, 0);
    // GCN4
    tgemm<<<dim3(GN,2), 256, 0, stream>>>(h3, NN, W4t, dinv, ybuf);
    gcn_agg_bf<<<5000, 256, 0, stream>>>(ybuf, dinv, rows, col, b4, h4, 1, 0);
    // GCN5 -> d_out (fp32)
    tgemm<<<dim3(GN,2), 256, 0, stream>>>(h4, NN, W5t, dinv, ybuf);
    gcn_agg_bf<<<5000, 256, 0, stream>>>(ybuf, dinv, rows, col, b5, outp, 0, 1);
}

// Round 14
// 559.982 us; speedup vs baseline: 1.0951x; 1.0014x over previous
//
#include <hip/hip_runtime.h>

#define NN 20000
#define EE 320000
#define KK 2000
#define KP 2048          // padded K-dim of E (zeros in 2000..2047)
#define SCALE 0.08838834764831845f
#define ZSPLIT 16        // attn_gemm partial slices
#define ACHUNKS 625      // 20000 / 32
#define ZCH 4            // s_gemm_exp k-chunks (4 * 512 = 2048)

typedef const float* cfp;
typedef __attribute__((ext_vector_type(8))) short sh8;
typedef __attribute__((ext_vector_type(4))) float f32x4;

static __device__ __forceinline__ float4 ld4(const float* p){ return *reinterpret_cast<const float4*>(p); }
static __device__ __forceinline__ void st4(float* p, float4 v){ *reinterpret_cast<float4*>(p) = v; }

static __device__ __forceinline__ unsigned short f2bf(float f){
    unsigned int u = __float_as_uint(f);
    u = (u + 0x7FFFu + ((u >> 16) & 1u)) >> 16;
    return (unsigned short)u;
}
static __device__ __forceinline__ float bf2f(unsigned short h){
    return __uint_as_float(((unsigned int)h) << 16);
}
static __device__ __forceinline__ sh8 lds8(const unsigned short* p){ return *reinterpret_cast<const sh8*>(p); }

// async global->LDS, 16B per lane; LDS dest is wave-uniform base + lane*16
static __device__ __forceinline__ void stage16(const unsigned short* g, unsigned short* l){
    __builtin_amdgcn_global_load_lds(
        (const __attribute__((address_space(1))) unsigned int*)g,
        (__attribute__((address_space(3))) unsigned int*)l, 16, 0, 0);
}

// ---------------- CSR build ----------------
__global__ __launch_bounds__(256) void k_count(const int* dst, int* deg){
    int i = blockIdx.x*256 + threadIdx.x;
    if (i < EE) atomicAdd(&deg[dst[i]], 1);
}

__global__ __launch_bounds__(256) void k_dinv(const int* deg, float* dinv){
    int n = blockIdx.x*256 + threadIdx.x;
    if (n < NN) dinv[n] = rsqrtf((float)deg[n] + 1.0f);
}

__global__ __launch_bounds__(1024) void k_scan(const int* cnt, int* rows){
    __shared__ int part[1024];
    int t = threadIdx.x;
    int base = t*20;
    int s = 0;
    for (int i = 0; i < 20; ++i){ int idx = base+i; if (idx < NN) s += cnt[idx]; }
    part[t] = s; __syncthreads();
    for (int off = 1; off < 1024; off <<= 1){
        int v = (t >= off) ? part[t-off] : 0;
        __syncthreads();
        part[t] += v;
        __syncthreads();
    }
    int run = part[t] - s;   // exclusive
    for (int i = 0; i < 20; ++i){
        int idx = base+i;
        if (idx < NN){ rows[idx] = run; run += cnt[idx]; }
    }
    if (t == 0) rows[NN] = EE;
}

__global__ __launch_bounds__(256) void k_fill(const int* src, const int* dst, const int* rows,
                                              int* cursor, int* col){
    int i = blockIdx.x*256 + threadIdx.x;
    if (i < EE){
        int d = dst[i];
        int pos = rows[d] + atomicAdd(&cursor[d], 1);
        col[pos] = src[i];
    }
}

// ---------------- weight transpose+convert ----------------
__global__ __launch_bounds__(256) void conv_wT(cfp w0, cfp w1, cfp w2, cfp w3, cfp w4, cfp w5, cfp w6,
                                               unsigned short* wts){
    const float* in;
    switch (blockIdx.z){
        case 0: in = w0; break; case 1: in = w1; break; case 2: in = w2; break;
        case 3: in = w3; break; case 4: in = w4; break; case 5: in = w5; break;
        default: in = w6; break;
    }
    unsigned short* out = wts + (size_t)blockIdx.z*16384;
    __shared__ float t[64][65];
    int r0 = blockIdx.x*64, c0 = blockIdx.y*64;
    int tid = threadIdx.x;
    for (int i = tid; i < 64*16; i += 256){
        int r = i >> 4, c4 = (i & 15) * 4;
        float4 v = ld4(in + (size_t)(r0+r)*128 + c0 + c4);
        t[r][c4+0]=v.x; t[r][c4+1]=v.y; t[r][c4+2]=v.z; t[r][c4+3]=v.w;
    }
    __syncthreads();
    for (int i = tid; i < 64*16; i += 256){
        int c = i >> 4, r4 = (i & 15) * 4;
        ushort4 o;
        o.x = f2bf(t[r4+0][c]); o.y = f2bf(t[r4+1][c]);
        o.z = f2bf(t[r4+2][c]); o.w = f2bf(t[r4+3][c]);
        *reinterpret_cast<ushort4*>(out + (size_t)(c0+c)*128 + r0 + r4) = o;
    }
}

// ---------------- fp32 GEMM (KK-sized only) ----------------
__global__ __launch_bounds__(512) void gemm128(const float* __restrict__ A, const float* __restrict__ Wm,
                                               float* __restrict__ C, int M,
                                               const float* bias, const float* resid, int relu){
    __shared__ __align__(16) float Ws[128*132];
    __shared__ float As[64*129];
    int tid = threadIdx.x;
    int r0 = blockIdx.x*64;
    for (int i = tid; i < 128*32; i += 512){
        int r = i >> 5, c4 = (i & 31) * 4;
        float4 v = ld4(Wm + r*128 + c4);
        st4(&Ws[r*132 + c4], v);
    }
    for (int i = tid; i < 64*32; i += 512){
        int r = i >> 5, c4 = (i & 31) * 4;
        float4 v = (r0 + r < M) ? ld4(A + (size_t)(r0+r)*128 + c4) : make_float4(0,0,0,0);
        As[r*129 + c4+0] = v.x; As[r*129 + c4+1] = v.y;
        As[r*129 + c4+2] = v.z; As[r*129 + c4+3] = v.w;
    }
    __syncthreads();
    int a = tid >> 5;
    int b = tid & 31;
    float acc[4][4] = {};
    #pragma unroll 4
    for (int d = 0; d < 128; ++d){
        float4 w = ld4(&Ws[d*132 + 4*b]);
        float wv[4] = {w.x, w.y, w.z, w.w};
        float av[4];
        #pragma unroll
        for (int i = 0; i < 4; ++i) av[i] = As[(4*a+i)*129 + d];
        #pragma unroll
        for (int i = 0; i < 4; ++i)
            #pragma unroll
            for (int j = 0; j < 4; ++j)
                acc[i][j] += av[i]*wv[j];
    }
    int cc = 4*b;
    #pragma unroll
    for (int i = 0; i < 4; ++i){
        int r = r0 + 4*a + i;
        if (r < M){
            float v[4];
            #pragma unroll
            for (int j = 0; j < 4; ++j) v[j] = acc[i][j];
            if (bias){
                #pragma unroll
                for (int j = 0; j < 4; ++j) v[j] += bias[cc+j];
            }
            if (relu){
                #pragma unroll
                for (int j = 0; j < 4; ++j) v[j] = fmaxf(v[j], 0.f);
            }
            if (resid){
                float4 rv = ld4(resid + (size_t)r*128 + cc);
                v[0]+=rv.x; v[1]+=rv.y; v[2]+=rv.z; v[3]+=rv.w;
            }
            st4(C + (size_t)r*128 + cc, make_float4(v[0],v[1],v[2],v[3]));
        }
    }
}

// ---------------- bf16 MFMA GEMM: C[M x 128] = (A@W)*rscale, bf16 out ----------------
__global__ __launch_bounds__(256) void tgemm(const unsigned short* __restrict__ A, int M,
                                             const unsigned short* __restrict__ Wt,
                                             const float* __restrict__ rscale,
                                             unsigned short* __restrict__ C){
    int tid = threadIdx.x;
    int wave = tid >> 6, lane = tid & 63;
    int wm = wave >> 1, wn = wave & 1;
    int m_base = blockIdx.x*64 + wm*32;
    int n_base = blockIdx.y*64 + wn*32;
    int l15 = lane & 15;
    int roff = (lane >> 4) * 8;
    const unsigned short* ap0 = A + (size_t)(m_base + l15)*128 + roff;
    const unsigned short* ap1 = ap0 + 16*128;
    const unsigned short* b0p = Wt + (size_t)(n_base + l15)*128 + roff;
    const unsigned short* b1p = b0p + 16*128;
    f32x4 acc00 = (f32x4)0.f, acc01 = (f32x4)0.f, acc10 = (f32x4)0.f, acc11 = (f32x4)0.f;
    #pragma unroll
    for (int r = 0; r < 128; r += 32){
        sh8 a0 = lds8(ap0 + r);
        sh8 a1 = lds8(ap1 + r);
        sh8 b0 = lds8(b0p + r);
        sh8 b1 = lds8(b1p + r);
        acc00 = __builtin_amdgcn_mfma_f32_16x16x32_bf16(a0, b0, acc00, 0, 0, 0);
        acc01 = __builtin_amdgcn_mfma_f32_16x16x32_bf16(a0, b1, acc01, 0, 0, 0);
        acc10 = __builtin_amdgcn_mfma_f32_16x16x32_bf16(a1, b0, acc10, 0, 0, 0);
        acc11 = __builtin_amdgcn_mfma_f32_16x16x32_bf16(a1, b1, acc11, 0, 0, 0);
    }
    int rq = (lane >> 4) * 4;
    f32x4 accs[2][2] = {{acc00, acc01},{acc10, acc11}};
    #pragma unroll
    for (int mi = 0; mi < 2; ++mi){
        #pragma unroll
        for (int ni = 0; ni < 2; ++ni){
            f32x4 a = accs[mi][ni];
            int gn = n_base + ni*16 + l15;
            #pragma unroll
            for (int reg = 0; reg < 4; ++reg){
                int gm = m_base + mi*16 + rq + reg;
                if (gm < M) C[(size_t)gm*128 + gn] = f2bf(a[reg] * (rscale ? rscale[gm] : 1.f));
            }
        }
    }
}

// ---------------- GCN aggregation: 2 nodes/wave, ushort4 per lane (2x gather MLP) ----------------
__global__ __launch_bounds__(256) void gcn_agg_bf(const unsigned short* __restrict__ y, const float* __restrict__ dinv,
                                                  const int* __restrict__ rows, const int* __restrict__ col,
                                                  const float* __restrict__ bias, void* __restrict__ outv,
                                                  int relu, int out_fp32){
    int wv = (int)((blockIdx.x*256 + threadIdx.x) >> 6);
    int lane = threadIdx.x & 63;
    int wid = wv*2 + (lane >> 5);     // half-wave owns one node
    if (wid >= NN) return;
    int f = (lane & 31) * 4;
    ushort4 u = *reinterpret_cast<const ushort4*>(y + (size_t)wid*128 + f);
    float a0 = bf2f(u.x), a1 = bf2f(u.y), a2 = bf2f(u.z), a3 = bf2f(u.w);
    int s = rows[wid], e = rows[wid+1];
    for (int j = s; j < e; j += 8){
        ushort4 v[8];
        #pragma unroll
        for (int q = 0; q < 8; ++q){
            int jj = (j + q < e) ? (j + q) : (e - 1);   // e>s guaranteed when body runs
            int c = col[jj];
            v[q] = *reinterpret_cast<const ushort4*>(y + (size_t)c*128 + f);
        }
        #pragma unroll
        for (int q = 0; q < 8; ++q){
            if (j + q < e){
                a0 += bf2f(v[q].x); a1 += bf2f(v[q].y);
                a2 += bf2f(v[q].z); a3 += bf2f(v[q].w);
            }
        }
    }
    float dn = dinv[wid];
    float o0 = a0*dn + bias[f+0];
    float o1 = a1*dn + bias[f+1];
    float o2 = a2*dn + bias[f+2];
    float o3 = a3*dn + bias[f+3];
    if (relu){ o0 = fmaxf(o0, 0.f); o1 = fmaxf(o1, 0.f); o2 = fmaxf(o2, 0.f); o3 = fmaxf(o3, 0.f); }
    if (out_fp32){
        st4((float*)outv + (size_t)wid*128 + f, make_float4(o0, o1, o2, o3));
    } else {
        ushort4 o; o.x = f2bf(o0); o.y = f2bf(o1); o.z = f2bf(o2); o.w = f2bf(o3);
        *reinterpret_cast<ushort4*>((unsigned short*)outv + (size_t)wid*128 + f) = o;
    }
}

// ---------------- fused K/V aggregation: one CSR walk, two gathers ----------------
// K: bf16 out (bias bk, no relu); V: fp32 out (bias bv, no relu).
__global__ __launch_bounds__(256) void gcn_agg_kv(const unsigned short* __restrict__ yk,
                                                  const unsigned short* __restrict__ yv,
                                                  const float* __restrict__ dinv,
                                                  const int* __restrict__ rows, const int* __restrict__ col,
                                                  const float* __restrict__ bk, const float* __restrict__ bv,
                                                  unsigned short* __restrict__ outk, float* __restrict__ outv){
    int wid = (int)((blockIdx.x*256 + threadIdx.x) >> 6);
    int lane = threadIdx.x & 63;
    if (wid >= NN) return;
    int f = lane*2;
    ushort2 uk = *reinterpret_cast<const ushort2*>(yk + (size_t)wid*128 + f);
    ushort2 uv = *reinterpret_cast<const ushort2*>(yv + (size_t)wid*128 + f);
    float kx = bf2f(uk.x), ky = bf2f(uk.y);
    float vx = bf2f(uv.x), vy = bf2f(uv.y);
    int s = rows[wid], e = rows[wid+1];
    int j = s;
    int e8 = s + ((e - s) & ~7);
    for (; j < e8; j += 8){
        ushort2 a[8], b[8];
        #pragma unroll
        for (int q = 0; q < 8; ++q){
            int c = col[j+q];
            a[q] = *reinterpret_cast<const ushort2*>(yk + (size_t)c*128 + f);
            b[q] = *reinterpret_cast<const ushort2*>(yv + (size_t)c*128 + f);
        }
        #pragma unroll
        for (int q = 0; q < 8; ++q){
            kx += bf2f(a[q].x); ky += bf2f(a[q].y);
            vx += bf2f(b[q].x); vy += bf2f(b[q].y);
        }
    }
    for (; j < e; ++j){
        int c0 = col[j];
        ushort2 a0 = *reinterpret_cast<const ushort2*>(yk + (size_t)c0*128 + f);
        ushort2 b0 = *reinterpret_cast<const ushort2*>(yv + (size_t)c0*128 + f);
        kx += bf2f(a0.x); ky += bf2f(a0.y);
        vx += bf2f(b0.x); vy += bf2f(b0.y);
    }
    float dn = dinv[wid];
    ushort2 ok;
    ok.x = f2bf(kx*dn + bk[f]);
    ok.y = f2bf(ky*dn + bk[f+1]);
    *reinterpret_cast<ushort2*>(outk + (size_t)wid*128 + f) = ok;
    *reinterpret_cast<float2*>(outv + (size_t)wid*128 + f) = make_float2(vx*dn + bv[f], vy*dn + bv[f+1]);
}

// ---------------- convert fp32 -> bf16 ----------------
__global__ __launch_bounds__(256) void conv_bf16(const float* __restrict__ in, unsigned short* __restrict__ out, int n4){
    int i = blockIdx.x*256 + threadIdx.x;
    if (i < n4){
        float4 v = ld4(in + (size_t)i*4);
        ushort4 o;
        o.x = f2bf(v.x); o.y = f2bf(v.y); o.z = f2bf(v.z); o.w = f2bf(v.w);
        *reinterpret_cast<ushort4*>(out + (size_t)i*4) = o;
    }
}

// ---------------- convert + transpose (+ optional per-source-row scale) ----------------
__global__ __launch_bounds__(256) void conv_bf16_T(const float* __restrict__ in, unsigned short* __restrict__ out,
                                                   int M, int ldout, const float* __restrict__ rscale){
    __shared__ float t[64][65];
    int r0 = blockIdx.x*64, c0 = blockIdx.y*64;
    int tid = threadIdx.x;
    for (int i = tid; i < 64*16; i += 256){
        int r = i >> 4, c4 = (i & 15) * 4;
        float4 v = (r0 + r < M) ? ld4(in + (size_t)(r0+r)*128 + c0 + c4) : make_float4(0,0,0,0);
        if (rscale && r0 + r < M){
            float sc = rscale[r0 + r];
            v.x *= sc; v.y *= sc; v.z *= sc; v.w *= sc;
        }
        t[r][c4+0]=v.x; t[r][c4+1]=v.y; t[r][c4+2]=v.z; t[r][c4+3]=v.w;
    }
    __syncthreads();
    for (int i = tid; i < 64*16; i += 256){
        int c = i >> 4, r4 = (i & 15) * 4;
        if (r0 + r4 < M){
            ushort4 o;
            o.x = f2bf(t[r4+0][c]); o.y = f2bf(t[r4+1][c]);
            o.z = f2bf(t[r4+2][c]); o.w = f2bf(t[r4+3][c]);
            *reinterpret_cast<ushort4*>(out + (size_t)(c0+c)*ldout + r0 + r4) = o;
        }
    }
}

// ---------------- z reduction: zinv[n] = 1/sum, zdinv[n] = zinv[n]*dinv[n] ----------------
__global__ __launch_bounds__(256) void k_rcp32(const float* __restrict__ zp, const float* __restrict__ dinv,
                                               float* __restrict__ zinv, float* __restrict__ zdinv){
    int n = blockIdx.x*256 + threadIdx.x;
    if (n < NN){
        float s = 0.f;
        #pragma unroll
        for (int y = 0; y < ZCH; ++y) s += zp[(size_t)y*NN + n];
        float zi = 1.f / s;
        zinv[n] = zi;
        zdinv[n] = zi * dinv[n];
    }
}

// ---------------- S-GEMM + exp + z-partials ----------------
// grid (313 n-blocks, ZCH k-chunks). Wave-private quadrant staging: each wave owns a
// 32x32 quadrant end-to-end (MFMA -> exp -> private LDS -> global), NO barriers in the
// k-loop (per-wave in-order DS pipe orders the LDS write->read). Waves slip freely.
__global__ __launch_bounds__(256) void s_gemm_exp(const unsigned short* __restrict__ Kb,
                                                  const unsigned short* __restrict__ Qb2,
                                                  unsigned short* __restrict__ E, float* __restrict__ zpart){
    __shared__ unsigned short Es[4][32*36];   // per-wave private quadrant, pad 36
    __shared__ float zsh[2][64];
    int tid = threadIdx.x;
    int wave = tid >> 6, lane = tid & 63;
    int wm = wave >> 1, wn = wave & 1;
    int n_blk = blockIdx.x*64;
    int k_base = blockIdx.y*512;
    int l15 = lane & 15;
    int h = lane >> 4;
    int roff = h * 8;
    int rq = h * 4;
    unsigned short* myEs = Es[wave];
    // Kd fragments (reused across all 8 k-blocks)
    const unsigned short* ap0 = Kb + (size_t)(n_blk + wm*32 + l15)*128 + roff;
    const unsigned short* ap1 = ap0 + 16*128;
    sh8 a0[4], a1[4];
    #pragma unroll
    for (int r = 0; r < 4; ++r){ a0[r] = lds8(ap0 + r*32); a1[r] = lds8(ap1 + r*32); }
    // Q fragments, double buffered
    const unsigned short* qbase = Qb2 + (size_t)(k_base + wn*32 + l15)*128 + roff;
    sh8 q0[4], q1[4];
    #pragma unroll
    for (int r = 0; r < 4; ++r){ q0[r] = lds8(qbase + r*32); q1[r] = lds8(qbase + 16*128 + r*32); }
    float zacc[2][4] = {{0.f,0.f,0.f,0.f},{0.f,0.f,0.f,0.f}};
    for (int kb = 0; kb < 8; ++kb){
        sh8 n0[4], n1[4];
        if (kb < 7){
            const unsigned short* qn = qbase + (size_t)(kb+1)*64*128;
            #pragma unroll
            for (int r = 0; r < 4; ++r){ n0[r] = lds8(qn + r*32); n1[r] = lds8(qn + 16*128 + r*32); }
        } else {
            #pragma unroll
            for (int r = 0; r < 4; ++r){ n0[r] = (sh8)0; n1[r] = (sh8)0; }
        }
        f32x4 acc00 = (f32x4)0.f, acc01 = (f32x4)0.f, acc10 = (f32x4)0.f, acc11 = (f32x4)0.f;
        #pragma unroll
        for (int r = 0; r < 4; ++r){
            acc00 = __builtin_amdgcn_mfma_f32_16x16x32_bf16(a0[r], q0[r], acc00, 0, 0, 0);
            acc01 = __builtin_amdgcn_mfma_f32_16x16x32_bf16(a0[r], q1[r], acc01, 0, 0, 0);
            acc10 = __builtin_amdgcn_mfma_f32_16x16x32_bf16(a1[r], q0[r], acc10, 0, 0, 0);
            acc11 = __builtin_amdgcn_mfma_f32_16x16x32_bf16(a1[r], q1[r], acc11, 0, 0, 0);
        }
        int kcol = k_base + kb*64;
        f32x4 accs[2][2] = {{acc00, acc01},{acc10, acc11}};
        // exp + write own quadrant to private LDS (rows 0..31 = quadrant rows, cols 0..31)
        #pragma unroll
        for (int mi = 0; mi < 2; ++mi){
            #pragma unroll
            for (int ni = 0; ni < 2; ++ni){
                f32x4 a = accs[mi][ni];
                bool kv = (kcol + wn*32 + ni*16 + l15) < KK;
                #pragma unroll
                for (int reg = 0; reg < 4; ++reg){
                    float e = kv ? __expf(a[reg]*SCALE) : 0.f;
                    myEs[(mi*16 + rq + reg)*36 + ni*16 + l15] = f2bf(e);
                    zacc[mi][reg] += e;
                }
            }
        }
        // read back own quadrant (b128) and store to global (64B row segments)
        #pragma unroll
        for (int it = 0; it < 2; ++it){
            int r = it*16 + (lane >> 2);
            int q4 = (lane & 3) * 8;
            sh8 v = lds8(myEs + r*36 + q4);
            int gr = n_blk + wm*32 + r;
            if (gr < NN)
                *reinterpret_cast<sh8*>(E + (size_t)gr*KP + kcol + wn*32 + q4) = v;
        }
        #pragma unroll
        for (int r = 0; r < 4; ++r){ q0[r] = n0[r]; q1[r] = n1[r]; }
    }
    // z reduction: sum over the 16 lanes of each l15-group (covers this wave's 32 cols)
    #pragma unroll
    for (int mi = 0; mi < 2; ++mi){
        #pragma unroll
        for (int reg = 0; reg < 4; ++reg){
            float v = zacc[mi][reg];
            v += __shfl_xor(v, 1);
            v += __shfl_xor(v, 2);
            v += __shfl_xor(v, 4);
            v += __shfl_xor(v, 8);
            zacc[mi][reg] = v;
        }
    }
    if (l15 == 0){
        #pragma unroll
        for (int mi = 0; mi < 2; ++mi)
            #pragma unroll
            for (int reg = 0; reg < 4; ++reg)
                zsh[wn][wm*32 + mi*16 + h*4 + reg] = zacc[mi][reg];
    }
    __syncthreads();
    if (tid < 64){
        int n = n_blk + tid;
        if (n < NN) zpart[(size_t)blockIdx.y*NN + n] = zsh[0][tid] + zsh[1][tid];
    }
}

// ---------------- attn GEMM partials with next-chunk prefetch ----------------
__global__ __launch_bounds__(256) void attn_gemm(const unsigned short* __restrict__ E,
                                                 const unsigned short* __restrict__ Vt,
                                                 float* __restrict__ part){
    __shared__ unsigned short As[64*36];
    int tid = threadIdx.x;
    int wave = tid >> 6, lane = tid & 63;
    int kk0 = blockIdx.x*64;
    int per = (ACHUNKS + ZSPLIT - 1) / ZSPLIT;
    int c0 = blockIdx.y*per;
    int c1 = min(ACHUNKS, c0 + per);
    int l15 = lane & 15;
    int q8 = (lane >> 4) * 8;
    int d0 = wave*32;
    int n_l = tid & 31;
    int k8 = (tid >> 5) * 8;
    f32x4 acc[4][2];
    #pragma unroll
    for (int g = 0; g < 4; ++g){ acc[g][0] = (f32x4)0.f; acc[g][1] = (f32x4)0.f; }
    const unsigned short* ebase = E + (size_t)n_l*KP + kk0 + k8;
    const unsigned short* vb0p = Vt + (size_t)(d0 + l15)*NN + q8;
    const unsigned short* vb1p = vb0p + (size_t)16*NN;
    sh8 etmp = lds8(ebase + (size_t)c0*32*KP);
    sh8 vb0 = lds8(vb0p + c0*32);
    sh8 vb1 = lds8(vb1p + c0*32);
    for (int ch = c0; ch < c1; ++ch){
        unsigned short tmp[8];
        *reinterpret_cast<sh8*>(tmp) = etmp;
        #pragma unroll
        for (int j = 0; j < 8; ++j) As[(k8 + j)*36 + n_l] = tmp[j];
        __syncthreads();
        sh8 etn = (sh8)0, vbn0 = (sh8)0, vbn1 = (sh8)0;
        if (ch + 1 < c1){
            etn  = lds8(ebase + (size_t)(ch+1)*32*KP);
            vbn0 = lds8(vb0p + (ch+1)*32);
            vbn1 = lds8(vb1p + (ch+1)*32);
        }
        #pragma unroll
        for (int g = 0; g < 4; ++g){
            const unsigned short* ap = &As[(g*16 + l15)*36 + q8];
            union { struct { ushort4 lo, hi; } u; sh8 v; } af;
            af.u.lo = *reinterpret_cast<const ushort4*>(ap);
            af.u.hi = *reinterpret_cast<const ushort4*>(ap + 4);
            acc[g][0] = __builtin_amdgcn_mfma_f32_16x16x32_bf16(af.v, vb0, acc[g][0], 0, 0, 0);
            acc[g][1] = __builtin_amdgcn_mfma_f32_16x16x32_bf16(af.v, vb1, acc[g][1], 0, 0, 0);
        }
        __syncthreads();
        etmp = etn; vb0 = vbn0; vb1 = vbn1;
    }
    float* pbase = part + (size_t)blockIdx.y*KK*128;
    int rq = (lane >> 4) * 4;
    #pragma unroll
    for (int g = 0; g < 4; ++g){
        #pragma unroll
        for (int ni = 0; ni < 2; ++ni){
            int d = d0 + ni*16 + l15;
            #pragma unroll
            for (int reg = 0; reg < 4; ++reg){
                int kk = kk0 + g*16 + rq + reg;
                if (kk < KK) pbase[(size_t)kk*128 + d] = acc[g][ni][reg];
            }
        }
    }
}

// ---------------- xout GEMM: full K=2048 sweep, LDS-staged E (swizzled), bf16 out fused with zdinv ----------------
// grid 625 blocks x 256 threads. Block: E rows [m_base, m_base+32), all 128 d-cols.
// E tile (32 rows x 128 k = 8KB) staged via global_load_lds, double-buffered.
// LDS layout: linear [row][kb], swizzle: LDS[row][kb] = E[row][kb ^ ((row&15)<<4)]
// (swizzle pre-applied to the GLOBAL source addr; read applies same XOR to the FULL in-row byte offset).
__global__ __launch_bounds__(256) void xout_gemm(const unsigned short* __restrict__ E,
                                                 const unsigned short* __restrict__ B,
                                                 const float* __restrict__ zdinv,
                                                 unsigned short* __restrict__ out){
    __shared__ __align__(16) unsigned short ebuf[2][4096];   // 2 x 8 KB
    int tid = threadIdx.x;
    int wave = tid >> 6, lane = tid & 63;
    int l15 = lane & 15;
    int h = lane >> 4;
    int m_base = blockIdx.x*32;
    int srow0 = wave*4 + h;            // issue 0 row (0..15)
    int skb0  = (l15*16) ^ ((srow0 & 15) << 4);
    int srow1 = 16 + srow0;            // issue 1 row (16..31)
    int skb1  = (l15*16) ^ ((srow1 & 15) << 4);
    const unsigned short* g0 = E + (size_t)(m_base + srow0)*KP + (skb0 >> 1);
    const unsigned short* g1 = E + (size_t)(m_base + srow1)*KP + (skb1 >> 1);
    unsigned short* l0 = &ebuf[0][wave*512];          // + issue*2048 ushorts
    unsigned short* l1 = &ebuf[1][wave*512];
    const unsigned short* bp0 = B + (size_t)(wave*32 + l15)*KP + h*8;
    const unsigned short* bp1 = bp0 + (size_t)16*KP;
    int rswz = l15 << 4;

    f32x4 acc[2][2];
    #pragma unroll
    for (int mi = 0; mi < 2; ++mi)
        #pragma unroll
        for (int ni = 0; ni < 2; ++ni) acc[mi][ni] = (f32x4)0.f;

    // prologue: stage tile 0, load B tile 0
    stage16(g0, l0);
    stage16(g1, l0 + 2048);
    sh8 b0[4], b1[4];
    #pragma unroll
    for (int s = 0; s < 4; ++s){ b0[s] = lds8(bp0 + s*32); b1[s] = lds8(bp1 + s*32); }
    __syncthreads();

    for (int t = 0; t < 16; ++t){
        if (t < 15){
            const unsigned short* ng0 = g0 + (t+1)*128;
            const unsigned short* ng1 = g1 + (t+1)*128;
            unsigned short* nl = (t & 1) ? l0 : l1;
            stage16(ng0, nl);
            stage16(ng1, nl + 2048);
        }
        sh8 nb0[4], nb1[4];
        if (t < 15){
            #pragma unroll
            for (int s = 0; s < 4; ++s){
                nb0[s] = lds8(bp0 + (t+1)*128 + s*32);
                nb1[s] = lds8(bp1 + (t+1)*128 + s*32);
            }
        } else {
            #pragma unroll
            for (int s = 0; s < 4; ++s){ nb0[s] = (sh8)0; nb1[s] = (sh8)0; }
        }
        const unsigned short* eb = (t & 1) ? ebuf[1] : ebuf[0];
        #pragma unroll
        for (int s = 0; s < 4; ++s){
            int ko = ((h*16 + s*64) ^ rswz) >> 1;     // ushort offset within row, stays < 128
            sh8 a0 = lds8(eb + l15*128 + ko);
            sh8 a1 = lds8(eb + (16 + l15)*128 + ko);
            acc[0][0] = __builtin_amdgcn_mfma_f32_16x16x32_bf16(a0, b0[s], acc[0][0], 0, 0, 0);
            acc[0][1] = __builtin_amdgcn_mfma_f32_16x16x32_bf16(a0, b1[s], acc[0][1], 0, 0, 0);
            acc[1][0] = __builtin_amdgcn_mfma_f32_16x16x32_bf16(a1, b0[s], acc[1][0], 0, 0, 0);
            acc[1][1] = __builtin_amdgcn_mfma_f32_16x16x32_bf16(a1, b1[s], acc[1][1], 0, 0, 0);
        }
        __syncthreads();
        #pragma unroll
        for (int s = 0; s < 4; ++s){ b0[s] = nb0[s]; b1[s] = nb1[s]; }
    }

    int rq = h*4;
    #pragma unroll
    for (int mi = 0; mi < 2; ++mi){
        #pragma unroll
        for (int ni = 0; ni < 2; ++ni){
            f32x4 a = acc[mi][ni];
            int d = wave*32 + ni*16 + l15;
            #pragma unroll
            for (int reg = 0; reg < 4; ++reg){
                int gm = m_base + mi*16 + rq + reg;
                out[(size_t)gm*128 + d] = f2bf(a[reg] * zdinv[gm]);
            }
        }
    }
}

// ---------------- LayerNorm over D=128 (with partial-sum input) ----------------
__global__ __launch_bounds__(128) void ln_ker(const float* __restrict__ in, int nparts,
                                              const float* __restrict__ resid,
                                              const float* __restrict__ g, const float* __restrict__ be,
                                              float* __restrict__ out){
    __shared__ float rs[128], rq[128];
    int r = blockIdx.x, t = threadIdx.x;
    float v = 0.f;
    for (int p = 0; p < nparts; ++p) v += in[(size_t)p*KK*128 + r*128 + t];
    if (resid) v += resid[r*128 + t];
    rs[t] = v; rq[t] = v*v;
    __syncthreads();
    for (int off = 64; off > 0; off >>= 1){
        if (t < off){ rs[t] += rs[t+off]; rq[t] += rq[t+off]; }
        __syncthreads();
    }
    float mean = rs[0]*(1.f/128.f);
    float var = rq[0]*(1.f/128.f) - mean*mean;
    out[r*128 + t] = (v - mean)*rsqrtf(var + 1e-5f)*g[t] + be[t];
}

// ---------------- launcher ----------------
extern "C" void kernel_launch(void* const* d_in, const int* in_sizes, int n_in,
                              void* d_out, int out_size, void* d_ws, size_t ws_size,
                              hipStream_t stream){
    cfp x  = (cfp)d_in[0];
    const int* ei = (const int*)d_in[1];
    const int* esrc = ei;
    const int* edst = ei + EE;
    cfp W1=(cfp)d_in[3], b1=(cfp)d_in[4], W2=(cfp)d_in[5], b2=(cfp)d_in[6];
    cfp S =(cfp)d_in[7];
    cfp Wq=(cfp)d_in[8],  bq=(cfp)d_in[9],  Wk=(cfp)d_in[10], bk=(cfp)d_in[11];
    cfp Wv=(cfp)d_in[12], bv=(cfp)d_in[13], Wo=(cfp)d_in[14], bo=(cfp)d_in[15];
    cfp g0=(cfp)d_in[16], be0=(cfp)d_in[17], g1=(cfp)d_in[18], be1=(cfp)d_in[19];
    cfp Wl=(cfp)d_in[20], bl=(cfp)d_in[21], W3=(cfp)d_in[22], b3=(cfp)d_in[23];
    cfp W4=(cfp)d_in[24], b4=(cfp)d_in[25], W5=(cfp)d_in[26], b5=(cfp)d_in[27];

    char* wsb = (char*)d_ws;
    const size_t MB = 1048576;
    int*   deg    = (int*)  (wsb + 0);
    float* dinv   = (float*)(wsb + 81920);
    int*   rows   = (int*)  (wsb + 163840);
    int*   cursor = (int*)  (wsb + 245760);
    int*   col    = (int*)  (wsb + 327680);
    float* Qb     = (float*)(wsb + 2*MB);
    float* o1     = (float*)(wsb + 3*MB);    // also xl3 (fp32)
    float* o2     = (float*)(wsb + 4*MB);
    float* o3     = (float*)(wsb + 5*MB);
    float* xlb    = (float*)(wsb + 6*MB);
    float* zpart  = (float*)(wsb + 7*MB);                 // ZCH x NN fp32
    float* zinv   = (float*)(wsb + 10*MB);
    float* zdinv  = (float*)(wsb + 10*MB + 131072);
    unsigned short* Wts  = (unsigned short*)(wsb + 10*MB + 262144);
    unsigned short* Qbf  = (unsigned short*)(wsb + 11*MB);
    unsigned short* xlt3 = (unsigned short*)(wsb + 11*MB + 524288);  // [128 x KP] bf16
    unsigned short* xbf = (unsigned short*)(wsb + 12*MB); // also h3
    unsigned short* h1  = (unsigned short*)(wsb + 17*MB); // also h4
    unsigned short* h2  = (unsigned short*)(wsb + 22*MB);
    unsigned short* ybuf= (unsigned short*)(wsb + 27*MB);
    unsigned short* Kbf = (unsigned short*)(wsb + 32*MB);
    unsigned short* Vtz = (unsigned short*)(wsb + 37*MB);
    // time-aliased region 42..62 MiB: NB3 (Vd fp32, 42..51.8) + ybufV (52..57, dead before part) -> part (16 MiB from 42)
    float* NB3    = (float*)(wsb + 42*MB);
    unsigned short* ybufV = (unsigned short*)(wsb + 52*MB);
    float* part   = (float*)(wsb + 42*MB);
    unsigned short* E = (unsigned short*)(wsb + 62*MB);   // [NN x KP] bf16 = 78.1 MiB -> ends ~140.1 MiB
    float* outp   = (float*)d_out;
    unsigned short* h3 = xbf;
    unsigned short* h4 = h1;

    (void)hipMemsetAsync(deg, 0, NN*sizeof(int), stream);
    (void)hipMemsetAsync(cursor, 0, NN*sizeof(int), stream);
    (void)hipMemsetAsync(xlt3, 0, 128*KP*sizeof(unsigned short), stream);  // pad cols must be finite

    // CSR build
    k_count<<<1250, 256, 0, stream>>>(edst, deg);
    k_dinv<<<79, 256, 0, stream>>>(deg, dinv);
    k_scan<<<1, 1024, 0, stream>>>(deg, rows);
    k_fill<<<1250, 256, 0, stream>>>(esrc, edst, rows, cursor, col);

    // weights -> bf16 transposed; x -> bf16
    conv_wT<<<dim3(2,2,7), 256, 0, stream>>>(W1, W2, Wk, Wv, W3, W4, W5, Wts);
    conv_bf16<<<2500, 256, 0, stream>>>(x, xbf, NN*32);
    unsigned short* W1t = Wts;
    unsigned short* W2t = Wts + 16384;
    unsigned short* Wkt = Wts + 2*16384;
    unsigned short* Wvt = Wts + 3*16384;
    unsigned short* W4t = Wts + 5*16384;
    unsigned short* W5t = Wts + 6*16384;

    const int GN = 313;   // ceil(NN/64)
    const int GK = 32;    // ceil(KK/64) == KP/64

    // GCN1
    tgemm<<<dim3(GN,2), 256, 0, stream>>>(xbf, NN, W1t, dinv, ybuf);
    gcn_agg_bf<<<2500, 256, 0, stream>>>(ybuf, dinv, rows, col, b1, h1, 1, 0);
    // GCN2 -> h2
    tgemm<<<dim3(GN,2), 256, 0, stream>>>(h1, NN, W2t, dinv, ybuf);
    gcn_agg_bf<<<2500, 256, 0, stream>>>(ybuf, dinv, rows, col, b2, h2, 1, 0);
    // K and V pre-agg GEMMs (both from h2), then ONE fused gather pass
    tgemm<<<dim3(GN,2), 256, 0, stream>>>(h2, NN, Wkt, dinv, ybuf);
    tgemm<<<dim3(GN,2), 256, 0, stream>>>(h2, NN, Wvt, dinv, ybufV);
    gcn_agg_kv<<<5000, 256, 0, stream>>>(ybuf, ybufV, dinv, rows, col, bk, bv, Kbf, NB3);
    // Q = S@Wq + bq (fp32) -> Qbf
    gemm128<<<GK, 512, 0, stream>>>(S, Wq, Qb, KK, bq, nullptr, 0);
    conv_bf16<<<250, 256, 0, stream>>>(Qb, Qbf, KK*32);
    // E = exp(SCALE * Kd Q^T), z partials (reg-cached Kd, 4 k-chunks, wave-private staging)
    s_gemm_exp<<<dim3(GN, ZCH), 256, 0, stream>>>(Kbf, Qbf, E, zpart);
    k_rcp32<<<79, 256, 0, stream>>>(zpart, dinv, zinv, zdinv);
    // Vd (NB3, fp32) -> Vtz (transposed bf16, pre-scaled by zinv[n])
    conv_bf16_T<<<dim3(GN, 2), 256, 0, stream>>>(NB3, Vtz, NN, NN, zinv);
    // attn partials (NB3/ybufV dead now; part aliases the region)
    attn_gemm<<<dim3(GK, ZSPLIT), 256, 0, stream>>>(E, Vtz, part);
    // out = LN(sum(part) + Q)
    ln_ker<<<KK, 128, 0, stream>>>(part, ZSPLIT, Qb, g0, be0, o1);
    // o2 = o1 + relu(o1@Wo + bo)
    gemm128<<<GK, 512, 0, stream>>>(o1, Wo, o2, KK, bo, o1, 1);
    ln_ker<<<KK, 128, 0, stream>>>(o2, 1, nullptr, g1, be1, o3);
    // xl = o3@Wl + bl ; xl3 = xl @ W3  (GCN3 weight folded into the seed side)
    gemm128<<<GK, 512, 0, stream>>>(o3, Wl, xlb, KK, bl, nullptr, 0);
    gemm128<<<GK, 512, 0, stream>>>(xlb, W3, o1, KK, nullptr, nullptr, 0);
    conv_bf16_T<<<dim3(GK, 2), 256, 0, stream>>>(o1, xlt3, KK, KP, nullptr);
    // ybuf[n] = bf16(zinv*dinv*(E[n] @ xl3)) == GCN3 pre-agg activations (fused, no partials)
    xout_gemm<<<625, 256, 0, stream>>>(E, xlt3, zdinv, ybuf);
    // GCN3 aggregation
    gcn_agg_bf<<<2500, 256, 0, stream>>>(ybuf, dinv, rows, col, b3, h3, 1, 0);
    // GCN4
    tgemm<<<dim3(GN,2), 256, 0, stream>>>(h3, NN, W4t, dinv, ybuf);
    gcn_agg_bf<<<2500, 256, 0, stream>>>(ybuf, dinv, rows, col, b4, h4, 1, 0);
    // GCN5 -> d_out (fp32)
    tgemm<<<dim3(GN,2), 256, 0, stream>>>(h4, NN, W5t, dinv, ybuf);
    gcn_agg_bf<<<2500, 256, 0, stream>>>(ybuf, dinv, rows, col, b5, outp, 0, 1);
}